// Round 4
// baseline (211.726 us; speedup 1.0000x reference)
//
#include <hip/hip_runtime.h>
#include <hip/hip_bf16.h>
#include <stdint.h>

typedef unsigned short u16;
typedef __attribute__((ext_vector_type(8))) short short8;
typedef __attribute__((ext_vector_type(4))) float f32x4;

#define B_ 2
#define S_ 2048
#define D_ 1024
#define H_ 16
#define DK_ 64
// scale folded into Q: (1/sqrt(DK)) * log2(e)  -> softmax done with exp2
#define QSCALE 0.18033688011112042f

__device__ __forceinline__ u16 f2bf(float f) {
  union { float f; uint32_t u; } c; c.f = f;
  uint32_t u = c.u;
  u += 0x7fffu + ((u >> 16) & 1u);
  return (u16)(u >> 16);
}

__device__ __forceinline__ uint32_t pk_bf16(float a, float b) {
  __hip_bfloat162 h = __float22bfloat162_rn(float2{a, b});
  union { __hip_bfloat162 h; uint32_t u; } c; c.h = h;
  return c.u;
}

__device__ __forceinline__ float fexp2(float x) {
#if __has_builtin(__builtin_amdgcn_exp2f)
  return __builtin_amdgcn_exp2f(x);
#else
  return exp2f(x);
#endif
}

__device__ __forceinline__ void gll16(const void* g, void* l) {
  __builtin_amdgcn_global_load_lds(
      (const __attribute__((address_space(1))) uint32_t*)g,
      (__attribute__((address_space(3))) uint32_t*)l, 16, 0, 0);
}

// ---------------- fused prep: cast hidden + Wq/Wk/Wv transpose + bias + Wo transpose
__global__ __launch_bounds__(256) void prep_k(const float* __restrict__ hidden,
                                              const float* __restrict__ Wq,
                                              const float* __restrict__ Wk,
                                              const float* __restrict__ Wv,
                                              const float* __restrict__ bq,
                                              const float* __restrict__ bk,
                                              const float* __restrict__ bv,
                                              const float* __restrict__ Wo,
                                              u16* __restrict__ Abf,
                                              u16* __restrict__ Wt,
                                              u16* __restrict__ Wot,
                                              float* __restrict__ biasQKV) {
  __shared__ float t[64][65];
  const int bx = blockIdx.x;
  const int tid = threadIdx.x;

  if (bx < 2048) {
    int i = (bx * 256 + tid) * 8;
    float4 a = *(const float4*)(hidden + i);
    float4 b = *(const float4*)(hidden + i + 4);
    short8 o;
    o[0] = (short)f2bf(a.x); o[1] = (short)f2bf(a.y);
    o[2] = (short)f2bf(a.z); o[3] = (short)f2bf(a.w);
    o[4] = (short)f2bf(b.x); o[5] = (short)f2bf(b.y);
    o[6] = (short)f2bf(b.z); o[7] = (short)f2bf(b.w);
    *(short8*)(Abf + i) = o;
    return;
  }

  if (bx < 2816) {
    const int blk = bx - 2048;
    const int by = blk & 15, z = blk >> 4;
    const int grp = z >> 4, h = z & 15;
    const float* src = (grp == 0) ? Wq : (grp == 1) ? Wk : Wv;
    const float* bsrc = (grp == 0) ? bq : (grp == 1) ? bk : bv;
    const float scale = (grp == 0) ? QSCALE : 1.0f;
    u16* dst = Wt + (size_t)grp * 1024 * 1024;
    const float* Sp = src + (size_t)h * 1024 * 64;
    const int r0 = by * 64;
#pragma unroll
    for (int i = 0; i < 4; i++) {
      int r = i * 16 + (tid >> 4), c = (tid & 15) * 4;
      float4 v = *(const float4*)(Sp + (size_t)(r0 + r) * 64 + c);
      t[r][c] = v.x; t[r][c + 1] = v.y; t[r][c + 2] = v.z; t[r][c + 3] = v.w;
    }
    if (by == 0 && tid < 64)
      biasQKV[grp * 1024 + h * 64 + tid] = bsrc[h * 64 + tid] * scale;
    __syncthreads();
#pragma unroll
    for (int i = 0; i < 4; i++) {
      int c = i * 16 + (tid >> 4), r = (tid & 15) * 4;
      ushort4 o;
      o.x = f2bf(t[r][c] * scale);
      o.y = f2bf(t[r + 1][c] * scale);
      o.z = f2bf(t[r + 2][c] * scale);
      o.w = f2bf(t[r + 3][c] * scale);
      *(ushort4*)(dst + (size_t)(h * 64 + c) * 1024 + r0 + r) = o;
    }
    return;
  }

  {
    const int blk = bx - 2816;
    const int c0 = (blk & 15) * 64, r0 = (blk >> 4) * 64;
#pragma unroll
    for (int i = 0; i < 4; i++) {
      int r = i * 16 + (tid >> 4), c = (tid & 15) * 4;
      float4 v = *(const float4*)(Wo + (size_t)(r0 + r) * 1024 + c0 + c);
      t[r][c] = v.x; t[r][c + 1] = v.y; t[r][c + 2] = v.z; t[r][c + 3] = v.w;
    }
    __syncthreads();
#pragma unroll
    for (int i = 0; i < 4; i++) {
      int c = i * 16 + (tid >> 4), r = (tid & 15) * 4;
      ushort4 o;
      o.x = f2bf(t[r][c]);
      o.y = f2bf(t[r + 1][c]);
      o.z = f2bf(t[r + 2][c]);
      o.w = f2bf(t[r + 3][c]);
      *(ushort4*)(Wot + (size_t)(c0 + c) * 1024 + r0 + r) = o;
    }
  }
}

// ---------------- QKV GEMM 128x128, BK=64, XOR-swizzled LDS ------------------
__global__ __launch_bounds__(256) void gemm_bt_k(const u16* __restrict__ A,
                                                 const u16* __restrict__ B,
                                                 const float* __restrict__ bias,
                                                 u16* __restrict__ Cout,
                                                 int M, int N, int K) {
  __shared__ u16 As[128 * 64];
  __shared__ u16 Bs[128 * 64];
  const int tid = threadIdx.x;
  const int w = tid >> 6, lane = tid & 63;
  const int wm = w >> 1, wn = w & 1;
  const int m0 = blockIdx.y * 128, n0 = blockIdx.x * 128;
  const int l15 = lane & 15, quad = lane >> 4;
  const int colr[2] = {(((quad) ^ (l15 & 7)) & 7) * 8,
                       (((4 + quad) ^ (l15 & 7)) & 7) * 8};

  int r_st[4], cs_st[4];
#pragma unroll
  for (int i = 0; i < 4; i++) {
    int idx = i * 256 + tid;
    r_st[i] = idx >> 3;
    cs_st[i] = ((idx & 7) ^ (r_st[i] & 7)) * 8;
  }

  f32x4 acc[4][4];
  const f32x4 zero = {0.f, 0.f, 0.f, 0.f};
#pragma unroll
  for (int i = 0; i < 4; i++)
#pragma unroll
    for (int j = 0; j < 4; j++) acc[i][j] = zero;

  for (int k0 = 0; k0 < K; k0 += 64) {
#pragma unroll
    for (int i = 0; i < 4; i++) {
      gll16(A + (size_t)(m0 + r_st[i]) * K + k0 + cs_st[i], &As[(i * 256 + w * 64) * 8]);
      gll16(B + (size_t)(n0 + r_st[i]) * K + k0 + cs_st[i], &Bs[(i * 256 + w * 64) * 8]);
    }
    __syncthreads();
#pragma unroll
    for (int kk = 0; kk < 2; kk++) {
      short8 af[4], bf[4];
#pragma unroll
      for (int i = 0; i < 4; i++) {
        af[i] = *(const short8*)&As[(wm * 64 + i * 16 + l15) * 64 + colr[kk]];
        bf[i] = *(const short8*)&Bs[(wn * 64 + i * 16 + l15) * 64 + colr[kk]];
      }
#pragma unroll
      for (int mi = 0; mi < 4; mi++)
#pragma unroll
        for (int ni = 0; ni < 4; ni++)
          acc[mi][ni] = __builtin_amdgcn_mfma_f32_16x16x32_bf16(af[mi], bf[ni], acc[mi][ni], 0, 0, 0);
    }
    __syncthreads();
  }

  const int cm = m0 + wm * 64, cn = n0 + wn * 64;
#pragma unroll
  for (int ni = 0; ni < 4; ni++) {
    int n = cn + ni * 16 + l15;
    float bv = bias[n];
#pragma unroll
    for (int mi = 0; mi < 4; mi++) {
#pragma unroll
      for (int r = 0; r < 4; r++) {
        int m = cm + mi * 16 + quad * 4 + r;
        Cout[(size_t)m * N + n] = f2bf(acc[mi][ni][r] + bv);
      }
    }
  }
}

// ---------------- GEMM 64x128 tile, fp32 out (out projection), swizzled ------
__global__ __launch_bounds__(256) void gemm_bt64_k(const u16* __restrict__ A,
                                                   const u16* __restrict__ B,
                                                   const float* __restrict__ bias,
                                                   float* __restrict__ Cout,
                                                   int M, int N, int K) {
  __shared__ u16 As[64 * 32];
  __shared__ u16 Bs[128 * 32];
  const int tid = threadIdx.x;
  const int w = tid >> 6, lane = tid & 63;
  const int wm = w >> 1, wn = w & 1;
  const int m0 = blockIdx.y * 64, n0 = blockIdx.x * 128;
  const int l15 = lane & 15, quad = lane >> 4;
  const int colq = ((quad ^ ((l15 >> 1) & 3)) & 3) * 8;

  int r_st[2], cs_st[2];
#pragma unroll
  for (int i = 0; i < 2; i++) {
    int idx = i * 256 + tid;
    r_st[i] = idx >> 2;
    cs_st[i] = (((idx & 3) ^ ((r_st[i] >> 1) & 3)) & 3) * 8;
  }

  f32x4 acc[2][4];
  const f32x4 zero = {0.f, 0.f, 0.f, 0.f};
#pragma unroll
  for (int i = 0; i < 2; i++)
#pragma unroll
    for (int j = 0; j < 4; j++) acc[i][j] = zero;

  for (int k0 = 0; k0 < K; k0 += 32) {
    gll16(A + (size_t)(m0 + r_st[0]) * K + k0 + cs_st[0], &As[(w * 64) * 8]);
#pragma unroll
    for (int i = 0; i < 2; i++)
      gll16(B + (size_t)(n0 + r_st[i]) * K + k0 + cs_st[i], &Bs[(i * 256 + w * 64) * 8]);
    __syncthreads();
    short8 af[2], bf[4];
#pragma unroll
    for (int i = 0; i < 2; i++)
      af[i] = *(const short8*)&As[(wm * 32 + i * 16 + l15) * 32 + colq];
#pragma unroll
    for (int j = 0; j < 4; j++)
      bf[j] = *(const short8*)&Bs[(wn * 64 + j * 16 + l15) * 32 + colq];
#pragma unroll
    for (int i = 0; i < 2; i++)
#pragma unroll
      for (int j = 0; j < 4; j++)
        acc[i][j] = __builtin_amdgcn_mfma_f32_16x16x32_bf16(af[i], bf[j], acc[i][j], 0, 0, 0);
    __syncthreads();
  }

  const int cm = m0 + wm * 32, cn = n0 + wn * 64;
#pragma unroll
  for (int j = 0; j < 4; j++) {
    int n = cn + j * 16 + l15;
    float bv = bias[n];
#pragma unroll
    for (int i = 0; i < 2; i++) {
#pragma unroll
      for (int r = 0; r < 4; r++) {
        int m = cm + i * 16 + quad * 4 + r;
        Cout[(size_t)m * N + n] = acc[i][j][r] + bv;
      }
    }
  }
}

// ---------------- V transpose: qkv V region -> Vt [b][h][v][s] bf16 ----------------
__global__ __launch_bounds__(256) void transpose_v_k(const u16* __restrict__ qkv,
                                                     u16* __restrict__ Vt) {
  __shared__ u16 t[64][71];
  const int b = blockIdx.z, h = blockIdx.y, s0 = blockIdx.x * 64;
  const int tid = threadIdx.x;
#pragma unroll
  for (int i = 0; i < 2; i++) {
    int s = i * 32 + (tid >> 3), v = (tid & 7) * 8;
    short8 val = *(const short8*)(qkv + (size_t)(b * S_ + s0 + s) * 3072 + 2048 + h * 64 + v);
#pragma unroll
    for (int j = 0; j < 8; j++) t[s][v + j] = (u16)val[j];
  }
  __syncthreads();
#pragma unroll
  for (int i = 0; i < 2; i++) {
    int v = i * 32 + (tid >> 3), s8 = (tid & 7) * 8;
    short8 o;
#pragma unroll
    for (int j = 0; j < 8; j++) o[j] = (short)t[s8 + j][v];
    *(short8*)(Vt + ((size_t)(b * H_ + h) * 64 + v) * S_ + s0 + s8) = o;
  }
}

// ---------------- flash attention (R8: R7 + XCD-aware swizzle + setprio) -----
// R7 data: occupancy 18->30% gave only -3.4us -> not occupancy-bound. New
// target: FETCH 69.7MB vs ~24MB distinct (4.4x K/V over-fetch). The 32 blocks
// sharing each (b,h)'s 512KB K/V were round-robined across 8 XCD L2s. Flat
// grid + bijective swizzle (1024 = 8*128): XCD g owns 4 COMPLETE (b,h) groups
// (2MB working set, fits 4MB L2) -> staged-load waits become L2-hit (~200cy)
// instead of HBM (~900cy) at the per-iter barrier drain. Plus T5 setprio
// around MFMA clusters (catalog: +4-7% on multi-wave attn).
__global__ __launch_bounds__(256, 4) void attn_k(const u16* __restrict__ qkv,
                                                 const u16* __restrict__ Vt,
                                                 u16* __restrict__ ctx) {
  __shared__ u16 Ks[2][64 * 64];
  __shared__ u16 Vs[2][64 * 64];
  const int tid = threadIdx.x;
  const int w = tid >> 6, lane = tid & 63;
  const int wq = w >> 1, wk = w & 1;
  const int l15 = lane & 15, quad = lane >> 4;

  // XCD-aware remap: xcd = orig%8 (dispatch round-robin); each xcd gets a
  // contiguous swz-range of 128 = 4 complete (b,h) groups of 32 q-blocks.
  const int orig = blockIdx.x;
  const int swz = (orig & 7) * 128 + (orig >> 3);
  const int q0 = (swz & 31) * 64;
  const int bh = swz >> 5;
  const int h = bh & 15, b = bh >> 4;

  short8 qf[2][2];
#pragma unroll
  for (int rt = 0; rt < 2; rt++) {
    const u16* qbase = qkv + (size_t)(b * S_ + q0 + wq * 32 + rt * 16 + l15) * 3072 + h * 64;
    qf[rt][0] = *(const short8*)(qbase + quad * 8);
    qf[rt][1] = *(const short8*)(qbase + 32 + quad * 8);
  }

  const int col0 = ((quad ^ (l15 & 7)) & 7) * 8;
  const int col1 = (((4 + quad) ^ (l15 & 7)) & 7) * 8;
  const int colw = wk ? col1 : col0;  // this wave's s-slice of V

  int r_st[2], cs_st[2];
#pragma unroll
  for (int i = 0; i < 2; i++) {
    int idx = i * 256 + tid;
    r_st[i] = idx >> 3;
    cs_st[i] = ((idx & 7) ^ (r_st[i] & 7)) * 8;
  }
  const u16* kp[2];
  const u16* vp[2];
#pragma unroll
  for (int i = 0; i < 2; i++) {
    kp[i] = qkv + (size_t)(b * S_ + r_st[i]) * 3072 + 1024 + h * 64 + cs_st[i];
    vp[i] = Vt + ((size_t)(b * H_ + h) * 64 + r_st[i]) * S_ + cs_st[i];
  }

  const f32x4 zero = {0.f, 0.f, 0.f, 0.f};
  f32x4 o[2][4];
#pragma unroll
  for (int rt = 0; rt < 2; rt++)
#pragma unroll
    for (int i = 0; i < 4; i++) o[rt][i] = zero;
  float lsum[2] = {0.f, 0.f};

  auto stage = [&](int bb, int t) {
#pragma unroll
    for (int i = 0; i < 2; i++) {
      gll16(kp[i] + (size_t)t * 64 * 3072, &Ks[bb][(i * 256 + w * 64) * 8]);
      gll16(vp[i] + t * 64, &Vs[bb][(i * 256 + w * 64) * 8]);
    }
  };

  auto compute = [&](int bb) {
    short8 kf[2][2];
#pragma unroll
    for (int kb = 0; kb < 2; kb++) {
      const int krow = (wk * 32 + kb * 16 + l15) * 64;
      kf[kb][0] = *(const short8*)&Ks[bb][krow + col0];
      kf[kb][1] = *(const short8*)&Ks[bb][krow + col1];
    }
    short8 pf[2];
#pragma unroll
    for (int rt = 0; rt < 2; rt++) {
      uint32_t Sx[2][2];
      __builtin_amdgcn_s_setprio(1);
#pragma unroll
      for (int kb = 0; kb < 2; kb++) {
        f32x4 st = __builtin_amdgcn_mfma_f32_16x16x32_bf16(kf[kb][0], qf[rt][0], zero, 0, 0, 0);
        st = __builtin_amdgcn_mfma_f32_16x16x32_bf16(kf[kb][1], qf[rt][1], st, 0, 0, 0);
        __builtin_amdgcn_s_setprio(0);
        float p0 = fexp2(st[0]), p1 = fexp2(st[1]), p2 = fexp2(st[2]), p3 = fexp2(st[3]);
        lsum[rt] += (p0 + p1) + (p2 + p3);
        Sx[kb][0] = pk_bf16(p0, p1);  // k = kb*16 + quad*4 + {0,1}
        Sx[kb][1] = pk_bf16(p2, p3);  // k = kb*16 + quad*4 + {2,3}
      }
#pragma unroll
      for (int s = 0; s < 2; s++)
        asm volatile("v_permlane32_swap_b32 %0, %1" : "+v"(Sx[0][s]), "+v"(Sx[1][s]));
#pragma unroll
      for (int s = 0; s < 2; s++)
        asm volatile("v_permlane16_swap_b32 %0, %1" : "+v"(Sx[0][s]), "+v"(Sx[1][s]));
      union { uint32_t u[4]; short8 s8; } cv;
      cv.u[0] = Sx[0][0]; cv.u[1] = Sx[0][1];
      cv.u[2] = Sx[1][0]; cv.u[3] = Sx[1][1];
      pf[rt] = cv.s8;
    }
    __builtin_amdgcn_s_setprio(1);
#pragma unroll
    for (int vi = 0; vi < 4; vi++) {
      short8 vf = *(const short8*)&Vs[bb][(vi * 16 + l15) * 64 + colw];
      o[0][vi] = __builtin_amdgcn_mfma_f32_16x16x32_bf16(vf, pf[0], o[0][vi], 0, 0, 0);
      o[1][vi] = __builtin_amdgcn_mfma_f32_16x16x32_bf16(vf, pf[1], o[1][vi], 0, 0, 0);
    }
    __builtin_amdgcn_s_setprio(0);
  };

  stage(0, 0);
  for (int t = 0; t < 31; t++) {
    __syncthreads();
    stage((t + 1) & 1, t + 1);
    compute(t & 1);
  }
  __syncthreads();
  compute(1);

  // ---- cross-wave (wk) reduction of O and lsum through freed LDS ----
  float ls[2];
#pragma unroll
  for (int rt = 0; rt < 2; rt++) {
    float l = lsum[rt];
    l += __shfl_xor(l, 16);
    l += __shfl_xor(l, 32);
    ls[rt] = l;
  }
  __syncthreads();  // all compute reads of Ks/Vs done before reuse
  float* red = (float*)&Ks[0][0];   // 16 KB: 2 wq-waves x 8 KB
  float* redl = (float*)&Vs[0][0];  // 1 KB
  if (wk == 1) {
#pragma unroll
    for (int rt = 0; rt < 2; rt++) {
#pragma unroll
      for (int vi = 0; vi < 4; vi++)
        *(f32x4*)(red + wq * 2048 + (rt * 4 + vi) * 256 + lane * 4) = o[rt][vi];
      redl[wq * 128 + rt * 64 + lane] = ls[rt];
    }
  }
  __syncthreads();
  if (wk == 0) {
#pragma unroll
    for (int rt = 0; rt < 2; rt++) {
      const float tot = ls[rt] + redl[wq * 128 + rt * 64 + lane];
      const float inv = 1.f / tot;
      u16* cbase = ctx + (size_t)(b * S_ + q0 + wq * 32 + rt * 16 + l15) * 1024 + h * 64;
#pragma unroll
      for (int vi = 0; vi < 4; vi++) {
        f32x4 p = *(f32x4*)(red + wq * 2048 + (rt * 4 + vi) * 256 + lane * 4);
        f32x4 s = o[rt][vi] + p;
        ushort4 pk;
        pk.x = f2bf(s[0] * inv);
        pk.y = f2bf(s[1] * inv);
        pk.z = f2bf(s[2] * inv);
        pk.w = f2bf(s[3] * inv);
        *(ushort4*)(cbase + vi * 16 + quad * 4) = pk;
      }
    }
  }
}

extern "C" void kernel_launch(void* const* d_in, const int* in_sizes, int n_in,
                              void* d_out, int out_size, void* d_ws, size_t ws_size,
                              hipStream_t stream) {
  const float* hidden = (const float*)d_in[0];
  const float* Wq = (const float*)d_in[1];
  const float* bq = (const float*)d_in[2];
  const float* Wk = (const float*)d_in[3];
  const float* bk = (const float*)d_in[4];
  const float* Wv = (const float*)d_in[5];
  const float* bv = (const float*)d_in[6];
  const float* Wo = (const float*)d_in[7];
  const float* bo = (const float*)d_in[8];
  float* out = (float*)d_out;

  char* ws = (char*)d_ws;
  u16* Abf = (u16*)(ws + 0);                 // 4096x1024 bf16   (8,388,608)
  u16* Wt = (u16*)(ws + 8388608);            // 3072x1024 bf16   (6,291,456)
  u16* Wot = (u16*)(ws + 14680064);          // 1024x1024 bf16   (2,097,152)
  float* biasQKV = (float*)(ws + 16777216);  // 3072 fp32        (12,288 padded)
  u16* qkv = (u16*)(ws + 16789504);          // 4096x3072 bf16   (25,165,824)
  u16* Vt = (u16*)(ws + 41955328);           // [b][h][64][2048] (8,388,608)
  u16* ctx = (u16*)(ws + 50343936);          // 4096x1024 bf16   (8,388,608)

  // fused prep: cast + Wq/Wk/Wv transpose + bias + Wo transpose
  prep_k<<<3072, 256, 0, stream>>>(hidden, Wq, Wk, Wv, bq, bk, bv, Wo,
                                   Abf, Wt, Wot, biasQKV);

  // QKV projection: [4096,1024] x [3072,1024]^T -> [4096,3072] bf16 (BK=64)
  gemm_bt_k<<<dim3(24, 32), 256, 0, stream>>>(Abf, Wt, biasQKV, qkv, 4096, 3072, 1024);

  // V transpose for PV A-operand
  transpose_v_k<<<dim3(32, 16, 2), 256, 0, stream>>>(qkv, Vt);

  // flash attention -> ctx [4096, 1024] bf16  (flat grid, XCD-aware swizzle)
  attn_k<<<dim3(1024), 256, 0, stream>>>(qkv, Vt, ctx);

  // output projection: [4096,1024] x [1024,1024]^T + bo -> fp32 out
  gemm_bt64_k<<<dim3(8, 64), 256, 0, stream>>>(ctx, Wot, bo, out, 4096, 1024, 1024);
}

// Round 5
// 207.042 us; speedup vs baseline: 1.0226x; 1.0226x over previous
//
#include <hip/hip_runtime.h>
#include <hip/hip_bf16.h>
#include <stdint.h>

typedef unsigned short u16;
typedef __attribute__((ext_vector_type(8))) short short8;
typedef __attribute__((ext_vector_type(4))) float f32x4;

#define B_ 2
#define S_ 2048
#define D_ 1024
#define H_ 16
#define DK_ 64
// scale folded into Q: (1/sqrt(DK)) * log2(e)  -> softmax done with exp2
#define QSCALE 0.18033688011112042f

__device__ __forceinline__ u16 f2bf(float f) {
  union { float f; uint32_t u; } c; c.f = f;
  uint32_t u = c.u;
  u += 0x7fffu + ((u >> 16) & 1u);
  return (u16)(u >> 16);
}

__device__ __forceinline__ uint32_t pk_bf16(float a, float b) {
  __hip_bfloat162 h = __float22bfloat162_rn(float2{a, b});
  union { __hip_bfloat162 h; uint32_t u; } c; c.h = h;
  return c.u;
}

__device__ __forceinline__ float fexp2(float x) {
#if __has_builtin(__builtin_amdgcn_exp2f)
  return __builtin_amdgcn_exp2f(x);
#else
  return exp2f(x);
#endif
}

__device__ __forceinline__ void gll16(const void* g, void* l) {
  __builtin_amdgcn_global_load_lds(
      (const __attribute__((address_space(1))) uint32_t*)g,
      (__attribute__((address_space(3))) uint32_t*)l, 16, 0, 0);
}

// ---------------- fused prep: cast hidden + Wq/Wk/Wv transpose + bias + Wo transpose
__global__ __launch_bounds__(256) void prep_k(const float* __restrict__ hidden,
                                              const float* __restrict__ Wq,
                                              const float* __restrict__ Wk,
                                              const float* __restrict__ Wv,
                                              const float* __restrict__ bq,
                                              const float* __restrict__ bk,
                                              const float* __restrict__ bv,
                                              const float* __restrict__ Wo,
                                              u16* __restrict__ Abf,
                                              u16* __restrict__ Wt,
                                              u16* __restrict__ Wot,
                                              float* __restrict__ biasQKV) {
  __shared__ float t[64][65];
  const int bx = blockIdx.x;
  const int tid = threadIdx.x;

  if (bx < 2048) {
    int i = (bx * 256 + tid) * 8;
    float4 a = *(const float4*)(hidden + i);
    float4 b = *(const float4*)(hidden + i + 4);
    short8 o;
    o[0] = (short)f2bf(a.x); o[1] = (short)f2bf(a.y);
    o[2] = (short)f2bf(a.z); o[3] = (short)f2bf(a.w);
    o[4] = (short)f2bf(b.x); o[5] = (short)f2bf(b.y);
    o[6] = (short)f2bf(b.z); o[7] = (short)f2bf(b.w);
    *(short8*)(Abf + i) = o;
    return;
  }

  if (bx < 2816) {
    const int blk = bx - 2048;
    const int by = blk & 15, z = blk >> 4;
    const int grp = z >> 4, h = z & 15;
    const float* src = (grp == 0) ? Wq : (grp == 1) ? Wk : Wv;
    const float* bsrc = (grp == 0) ? bq : (grp == 1) ? bk : bv;
    const float scale = (grp == 0) ? QSCALE : 1.0f;
    u16* dst = Wt + (size_t)grp * 1024 * 1024;
    const float* Sp = src + (size_t)h * 1024 * 64;
    const int r0 = by * 64;
#pragma unroll
    for (int i = 0; i < 4; i++) {
      int r = i * 16 + (tid >> 4), c = (tid & 15) * 4;
      float4 v = *(const float4*)(Sp + (size_t)(r0 + r) * 64 + c);
      t[r][c] = v.x; t[r][c + 1] = v.y; t[r][c + 2] = v.z; t[r][c + 3] = v.w;
    }
    if (by == 0 && tid < 64)
      biasQKV[grp * 1024 + h * 64 + tid] = bsrc[h * 64 + tid] * scale;
    __syncthreads();
#pragma unroll
    for (int i = 0; i < 4; i++) {
      int c = i * 16 + (tid >> 4), r = (tid & 15) * 4;
      ushort4 o;
      o.x = f2bf(t[r][c] * scale);
      o.y = f2bf(t[r + 1][c] * scale);
      o.z = f2bf(t[r + 2][c] * scale);
      o.w = f2bf(t[r + 3][c] * scale);
      *(ushort4*)(dst + (size_t)(h * 64 + c) * 1024 + r0 + r) = o;
    }
    return;
  }

  {
    const int blk = bx - 2816;
    const int c0 = (blk & 15) * 64, r0 = (blk >> 4) * 64;
#pragma unroll
    for (int i = 0; i < 4; i++) {
      int r = i * 16 + (tid >> 4), c = (tid & 15) * 4;
      float4 v = *(const float4*)(Wo + (size_t)(r0 + r) * 1024 + c0 + c);
      t[r][c] = v.x; t[r][c + 1] = v.y; t[r][c + 2] = v.z; t[r][c + 3] = v.w;
    }
    __syncthreads();
#pragma unroll
    for (int i = 0; i < 4; i++) {
      int c = i * 16 + (tid >> 4), r = (tid & 15) * 4;
      ushort4 o;
      o.x = f2bf(t[r][c]);
      o.y = f2bf(t[r + 1][c]);
      o.z = f2bf(t[r + 2][c]);
      o.w = f2bf(t[r + 3][c]);
      *(ushort4*)(Wot + (size_t)(c0 + c) * 1024 + r0 + r) = o;
    }
  }
}

// ---------------- QKV GEMM 128x128, BK=64, XOR-swizzled LDS ------------------
// R9: XCD-aware flat grid (768 = 8 XCDs x (24 n x 4 m)). Each XCD owns an
// A-band of 4 block-rows (512 rows, 1MB) and walks n with m innermost ->
// steady per-XCD L2 working set ~1.25MB (A-band + current B col). Kills the
// cross-XCD panel re-fetch (A read 24x, B read 32x when scattered).
__global__ __launch_bounds__(256) void gemm_bt_k(const u16* __restrict__ A,
                                                 const u16* __restrict__ B,
                                                 const float* __restrict__ bias,
                                                 u16* __restrict__ Cout,
                                                 int M, int N, int K) {
  __shared__ u16 As[128 * 64];
  __shared__ u16 Bs[128 * 64];
  const int tid = threadIdx.x;
  const int w = tid >> 6, lane = tid & 63;
  const int wm = w >> 1, wn = w & 1;
  const int orig = blockIdx.x;
  const int xcd = orig & 7, idx = orig >> 3;
  const int ni = idx >> 2, mi_ = idx & 3;
  const int m0 = (xcd * 4 + mi_) * 128, n0 = ni * 128;
  const int l15 = lane & 15, quad = lane >> 4;
  const int colr[2] = {(((quad) ^ (l15 & 7)) & 7) * 8,
                       (((4 + quad) ^ (l15 & 7)) & 7) * 8};

  int r_st[4], cs_st[4];
#pragma unroll
  for (int i = 0; i < 4; i++) {
    int idx2 = i * 256 + tid;
    r_st[i] = idx2 >> 3;
    cs_st[i] = ((idx2 & 7) ^ (r_st[i] & 7)) * 8;
  }

  f32x4 acc[4][4];
  const f32x4 zero = {0.f, 0.f, 0.f, 0.f};
#pragma unroll
  for (int i = 0; i < 4; i++)
#pragma unroll
    for (int j = 0; j < 4; j++) acc[i][j] = zero;

  for (int k0 = 0; k0 < K; k0 += 64) {
#pragma unroll
    for (int i = 0; i < 4; i++) {
      gll16(A + (size_t)(m0 + r_st[i]) * K + k0 + cs_st[i], &As[(i * 256 + w * 64) * 8]);
      gll16(B + (size_t)(n0 + r_st[i]) * K + k0 + cs_st[i], &Bs[(i * 256 + w * 64) * 8]);
    }
    __syncthreads();
#pragma unroll
    for (int kk = 0; kk < 2; kk++) {
      short8 af[4], bf[4];
#pragma unroll
      for (int i = 0; i < 4; i++) {
        af[i] = *(const short8*)&As[(wm * 64 + i * 16 + l15) * 64 + colr[kk]];
        bf[i] = *(const short8*)&Bs[(wn * 64 + i * 16 + l15) * 64 + colr[kk]];
      }
#pragma unroll
      for (int mi = 0; mi < 4; mi++)
#pragma unroll
        for (int ni2 = 0; ni2 < 4; ni2++)
          acc[mi][ni2] = __builtin_amdgcn_mfma_f32_16x16x32_bf16(af[mi], bf[ni2], acc[mi][ni2], 0, 0, 0);
    }
    __syncthreads();
  }

  const int cm = m0 + wm * 64, cn = n0 + wn * 64;
#pragma unroll
  for (int ni2 = 0; ni2 < 4; ni2++) {
    int n = cn + ni2 * 16 + l15;
    float bv = bias[n];
#pragma unroll
    for (int mi = 0; mi < 4; mi++) {
#pragma unroll
      for (int r = 0; r < 4; r++) {
        int m = cm + mi * 16 + quad * 4 + r;
        Cout[(size_t)m * N + n] = f2bf(acc[mi][ni2][r] + bv);
      }
    }
  }
}

// ---------------- GEMM 64x128 tile, fp32 out (out projection), swizzled ------
// R9: XCD-aware flat grid (512 = 8 XCDs x (8 n x 8 m)); per-XCD A-band 1MB +
// current B col 0.25MB stays L2-resident.
__global__ __launch_bounds__(256) void gemm_bt64_k(const u16* __restrict__ A,
                                                   const u16* __restrict__ B,
                                                   const float* __restrict__ bias,
                                                   float* __restrict__ Cout,
                                                   int M, int N, int K) {
  __shared__ u16 As[64 * 32];
  __shared__ u16 Bs[128 * 32];
  const int tid = threadIdx.x;
  const int w = tid >> 6, lane = tid & 63;
  const int wm = w >> 1, wn = w & 1;
  const int orig = blockIdx.x;
  const int xcd = orig & 7, idx = orig >> 3;
  const int ni = idx >> 3, mi_ = idx & 7;
  const int m0 = (xcd * 8 + mi_) * 64, n0 = ni * 128;
  const int l15 = lane & 15, quad = lane >> 4;
  const int colq = ((quad ^ ((l15 >> 1) & 3)) & 3) * 8;

  int r_st[2], cs_st[2];
#pragma unroll
  for (int i = 0; i < 2; i++) {
    int idx2 = i * 256 + tid;
    r_st[i] = idx2 >> 2;
    cs_st[i] = (((idx2 & 3) ^ ((r_st[i] >> 1) & 3)) & 3) * 8;
  }

  f32x4 acc[2][4];
  const f32x4 zero = {0.f, 0.f, 0.f, 0.f};
#pragma unroll
  for (int i = 0; i < 2; i++)
#pragma unroll
    for (int j = 0; j < 4; j++) acc[i][j] = zero;

  for (int k0 = 0; k0 < K; k0 += 32) {
    gll16(A + (size_t)(m0 + r_st[0]) * K + k0 + cs_st[0], &As[(w * 64) * 8]);
#pragma unroll
    for (int i = 0; i < 2; i++)
      gll16(B + (size_t)(n0 + r_st[i]) * K + k0 + cs_st[i], &Bs[(i * 256 + w * 64) * 8]);
    __syncthreads();
    short8 af[2], bf[4];
#pragma unroll
    for (int i = 0; i < 2; i++)
      af[i] = *(const short8*)&As[(wm * 32 + i * 16 + l15) * 32 + colq];
#pragma unroll
    for (int j = 0; j < 4; j++)
      bf[j] = *(const short8*)&Bs[(wn * 64 + j * 16 + l15) * 32 + colq];
#pragma unroll
    for (int i = 0; i < 2; i++)
#pragma unroll
      for (int j = 0; j < 4; j++)
        acc[i][j] = __builtin_amdgcn_mfma_f32_16x16x32_bf16(af[i], bf[j], acc[i][j], 0, 0, 0);
    __syncthreads();
  }

  const int cm = m0 + wm * 32, cn = n0 + wn * 64;
#pragma unroll
  for (int j = 0; j < 4; j++) {
    int n = cn + j * 16 + l15;
    float bv = bias[n];
#pragma unroll
    for (int i = 0; i < 2; i++) {
#pragma unroll
      for (int r = 0; r < 4; r++) {
        int m = cm + i * 16 + quad * 4 + r;
        Cout[(size_t)m * N + n] = acc[i][j][r] + bv;
      }
    }
  }
}

// ---------------- V transpose: qkv V region -> Vt [b][h][v][s] bf16 ----------------
__global__ __launch_bounds__(256) void transpose_v_k(const u16* __restrict__ qkv,
                                                     u16* __restrict__ Vt) {
  __shared__ u16 t[64][71];
  const int b = blockIdx.z, h = blockIdx.y, s0 = blockIdx.x * 64;
  const int tid = threadIdx.x;
#pragma unroll
  for (int i = 0; i < 2; i++) {
    int s = i * 32 + (tid >> 3), v = (tid & 7) * 8;
    short8 val = *(const short8*)(qkv + (size_t)(b * S_ + s0 + s) * 3072 + 2048 + h * 64 + v);
#pragma unroll
    for (int j = 0; j < 8; j++) t[s][v + j] = (u16)val[j];
  }
  __syncthreads();
#pragma unroll
  for (int i = 0; i < 2; i++) {
    int v = i * 32 + (tid >> 3), s8 = (tid & 7) * 8;
    short8 o;
#pragma unroll
    for (int j = 0; j < 8; j++) o[j] = (short)t[s8 + j][v];
    *(short8*)(Vt + ((size_t)(b * H_ + h) * 64 + v) * S_ + s0 + s8) = o;
  }
}

// ---------------- flash attention (R8 config, kept: proven ~57us floor) ------
// History: R6 killed LDS P-roundtrip (conflicts->0, no dur change). R7 doubled
// occupancy (no dur change). R8 XCD swizzle: FETCH 69.7->12.3MB (L2-resident)
// but dur -1.3us only. All pipes <50% -> issue/dependency floor under this
// schedule. Do not micro-tweak further; a different sync template would be
// needed for more.
__global__ __launch_bounds__(256, 4) void attn_k(const u16* __restrict__ qkv,
                                                 const u16* __restrict__ Vt,
                                                 u16* __restrict__ ctx) {
  __shared__ u16 Ks[2][64 * 64];
  __shared__ u16 Vs[2][64 * 64];
  const int tid = threadIdx.x;
  const int w = tid >> 6, lane = tid & 63;
  const int wq = w >> 1, wk = w & 1;
  const int l15 = lane & 15, quad = lane >> 4;

  // XCD-aware remap: xcd = orig%8 (dispatch round-robin); each xcd gets a
  // contiguous swz-range of 128 = 4 complete (b,h) groups of 32 q-blocks.
  const int orig = blockIdx.x;
  const int swz = (orig & 7) * 128 + (orig >> 3);
  const int q0 = (swz & 31) * 64;
  const int bh = swz >> 5;
  const int h = bh & 15, b = bh >> 4;

  short8 qf[2][2];
#pragma unroll
  for (int rt = 0; rt < 2; rt++) {
    const u16* qbase = qkv + (size_t)(b * S_ + q0 + wq * 32 + rt * 16 + l15) * 3072 + h * 64;
    qf[rt][0] = *(const short8*)(qbase + quad * 8);
    qf[rt][1] = *(const short8*)(qbase + 32 + quad * 8);
  }

  const int col0 = ((quad ^ (l15 & 7)) & 7) * 8;
  const int col1 = (((4 + quad) ^ (l15 & 7)) & 7) * 8;
  const int colw = wk ? col1 : col0;  // this wave's s-slice of V

  int r_st[2], cs_st[2];
#pragma unroll
  for (int i = 0; i < 2; i++) {
    int idx = i * 256 + tid;
    r_st[i] = idx >> 3;
    cs_st[i] = ((idx & 7) ^ (r_st[i] & 7)) * 8;
  }
  const u16* kp[2];
  const u16* vp[2];
#pragma unroll
  for (int i = 0; i < 2; i++) {
    kp[i] = qkv + (size_t)(b * S_ + r_st[i]) * 3072 + 1024 + h * 64 + cs_st[i];
    vp[i] = Vt + ((size_t)(b * H_ + h) * 64 + r_st[i]) * S_ + cs_st[i];
  }

  const f32x4 zero = {0.f, 0.f, 0.f, 0.f};
  f32x4 o[2][4];
#pragma unroll
  for (int rt = 0; rt < 2; rt++)
#pragma unroll
    for (int i = 0; i < 4; i++) o[rt][i] = zero;
  float lsum[2] = {0.f, 0.f};

  auto stage = [&](int bb, int t) {
#pragma unroll
    for (int i = 0; i < 2; i++) {
      gll16(kp[i] + (size_t)t * 64 * 3072, &Ks[bb][(i * 256 + w * 64) * 8]);
      gll16(vp[i] + t * 64, &Vs[bb][(i * 256 + w * 64) * 8]);
    }
  };

  auto compute = [&](int bb) {
    short8 kf[2][2];
#pragma unroll
    for (int kb = 0; kb < 2; kb++) {
      const int krow = (wk * 32 + kb * 16 + l15) * 64;
      kf[kb][0] = *(const short8*)&Ks[bb][krow + col0];
      kf[kb][1] = *(const short8*)&Ks[bb][krow + col1];
    }
    short8 pf[2];
#pragma unroll
    for (int rt = 0; rt < 2; rt++) {
      uint32_t Sx[2][2];
      __builtin_amdgcn_s_setprio(1);
#pragma unroll
      for (int kb = 0; kb < 2; kb++) {
        f32x4 st = __builtin_amdgcn_mfma_f32_16x16x32_bf16(kf[kb][0], qf[rt][0], zero, 0, 0, 0);
        st = __builtin_amdgcn_mfma_f32_16x16x32_bf16(kf[kb][1], qf[rt][1], st, 0, 0, 0);
        __builtin_amdgcn_s_setprio(0);
        float p0 = fexp2(st[0]), p1 = fexp2(st[1]), p2 = fexp2(st[2]), p3 = fexp2(st[3]);
        lsum[rt] += (p0 + p1) + (p2 + p3);
        Sx[kb][0] = pk_bf16(p0, p1);  // k = kb*16 + quad*4 + {0,1}
        Sx[kb][1] = pk_bf16(p2, p3);  // k = kb*16 + quad*4 + {2,3}
      }
#pragma unroll
      for (int s = 0; s < 2; s++)
        asm volatile("v_permlane32_swap_b32 %0, %1" : "+v"(Sx[0][s]), "+v"(Sx[1][s]));
#pragma unroll
      for (int s = 0; s < 2; s++)
        asm volatile("v_permlane16_swap_b32 %0, %1" : "+v"(Sx[0][s]), "+v"(Sx[1][s]));
      union { uint32_t u[4]; short8 s8; } cv;
      cv.u[0] = Sx[0][0]; cv.u[1] = Sx[0][1];
      cv.u[2] = Sx[1][0]; cv.u[3] = Sx[1][1];
      pf[rt] = cv.s8;
    }
    __builtin_amdgcn_s_setprio(1);
#pragma unroll
    for (int vi = 0; vi < 4; vi++) {
      short8 vf = *(const short8*)&Vs[bb][(vi * 16 + l15) * 64 + colw];
      o[0][vi] = __builtin_amdgcn_mfma_f32_16x16x32_bf16(vf, pf[0], o[0][vi], 0, 0, 0);
      o[1][vi] = __builtin_amdgcn_mfma_f32_16x16x32_bf16(vf, pf[1], o[1][vi], 0, 0, 0);
    }
    __builtin_amdgcn_s_setprio(0);
  };

  stage(0, 0);
  for (int t = 0; t < 31; t++) {
    __syncthreads();
    stage((t + 1) & 1, t + 1);
    compute(t & 1);
  }
  __syncthreads();
  compute(1);

  // ---- cross-wave (wk) reduction of O and lsum through freed LDS ----
  float ls[2];
#pragma unroll
  for (int rt = 0; rt < 2; rt++) {
    float l = lsum[rt];
    l += __shfl_xor(l, 16);
    l += __shfl_xor(l, 32);
    ls[rt] = l;
  }
  __syncthreads();  // all compute reads of Ks/Vs done before reuse
  float* red = (float*)&Ks[0][0];   // 16 KB: 2 wq-waves x 8 KB
  float* redl = (float*)&Vs[0][0];  // 1 KB
  if (wk == 1) {
#pragma unroll
    for (int rt = 0; rt < 2; rt++) {
#pragma unroll
      for (int vi = 0; vi < 4; vi++)
        *(f32x4*)(red + wq * 2048 + (rt * 4 + vi) * 256 + lane * 4) = o[rt][vi];
      redl[wq * 128 + rt * 64 + lane] = ls[rt];
    }
  }
  __syncthreads();
  if (wk == 0) {
#pragma unroll
    for (int rt = 0; rt < 2; rt++) {
      const float tot = ls[rt] + redl[wq * 128 + rt * 64 + lane];
      const float inv = 1.f / tot;
      u16* cbase = ctx + (size_t)(b * S_ + q0 + wq * 32 + rt * 16 + l15) * 1024 + h * 64;
#pragma unroll
      for (int vi = 0; vi < 4; vi++) {
        f32x4 p = *(f32x4*)(red + wq * 2048 + (rt * 4 + vi) * 256 + lane * 4);
        f32x4 s = o[rt][vi] + p;
        ushort4 pk;
        pk.x = f2bf(s[0] * inv);
        pk.y = f2bf(s[1] * inv);
        pk.z = f2bf(s[2] * inv);
        pk.w = f2bf(s[3] * inv);
        *(ushort4*)(cbase + vi * 16 + quad * 4) = pk;
      }
    }
  }
}

extern "C" void kernel_launch(void* const* d_in, const int* in_sizes, int n_in,
                              void* d_out, int out_size, void* d_ws, size_t ws_size,
                              hipStream_t stream) {
  const float* hidden = (const float*)d_in[0];
  const float* Wq = (const float*)d_in[1];
  const float* bq = (const float*)d_in[2];
  const float* Wk = (const float*)d_in[3];
  const float* bk = (const float*)d_in[4];
  const float* Wv = (const float*)d_in[5];
  const float* bv = (const float*)d_in[6];
  const float* Wo = (const float*)d_in[7];
  const float* bo = (const float*)d_in[8];
  float* out = (float*)d_out;

  char* ws = (char*)d_ws;
  u16* Abf = (u16*)(ws + 0);                 // 4096x1024 bf16   (8,388,608)
  u16* Wt = (u16*)(ws + 8388608);            // 3072x1024 bf16   (6,291,456)
  u16* Wot = (u16*)(ws + 14680064);          // 1024x1024 bf16   (2,097,152)
  float* biasQKV = (float*)(ws + 16777216);  // 3072 fp32        (12,288 padded)
  u16* qkv = (u16*)(ws + 16789504);          // 4096x3072 bf16   (25,165,824)
  u16* Vt = (u16*)(ws + 41955328);           // [b][h][64][2048] (8,388,608)
  u16* ctx = (u16*)(ws + 50343936);          // 4096x1024 bf16   (8,388,608)

  // fused prep: cast + Wq/Wk/Wv transpose + bias + Wo transpose
  prep_k<<<3072, 256, 0, stream>>>(hidden, Wq, Wk, Wv, bq, bk, bv, Wo,
                                   Abf, Wt, Wot, biasQKV);

  // QKV projection: [4096,1024] x [3072,1024]^T -> [4096,3072] bf16 (BK=64)
  // flat grid, XCD-aware decode inside
  gemm_bt_k<<<dim3(768), 256, 0, stream>>>(Abf, Wt, biasQKV, qkv, 4096, 3072, 1024);

  // V transpose for PV A-operand
  transpose_v_k<<<dim3(32, 16, 2), 256, 0, stream>>>(qkv, Vt);

  // flash attention -> ctx [4096, 1024] bf16  (flat grid, XCD-aware swizzle)
  attn_k<<<dim3(1024), 256, 0, stream>>>(qkv, Vt, ctx);

  // output projection: [4096,1024] x [1024,1024]^T + bo -> fp32 out
  gemm_bt64_k<<<dim3(512), 256, 0, stream>>>(ctx, Wot, bo, out, 4096, 1024, 1024);
}

// Round 6
// 201.971 us; speedup vs baseline: 1.0483x; 1.0251x over previous
//
#include <hip/hip_runtime.h>
#include <hip/hip_bf16.h>
#include <stdint.h>

typedef unsigned short u16;
typedef __attribute__((ext_vector_type(8))) short short8;
typedef __attribute__((ext_vector_type(4))) float f32x4;

#define B_ 2
#define S_ 2048
#define D_ 1024
#define H_ 16
#define DK_ 64
// scale folded into Q: (1/sqrt(DK)) * log2(e)  -> softmax done with exp2
#define QSCALE 0.18033688011112042f

__device__ __forceinline__ u16 f2bf(float f) {
  union { float f; uint32_t u; } c; c.f = f;
  uint32_t u = c.u;
  u += 0x7fffu + ((u >> 16) & 1u);
  return (u16)(u >> 16);
}

__device__ __forceinline__ uint32_t pk_bf16(float a, float b) {
  __hip_bfloat162 h = __float22bfloat162_rn(float2{a, b});
  union { __hip_bfloat162 h; uint32_t u; } c; c.h = h;
  return c.u;
}

__device__ __forceinline__ float fexp2(float x) {
#if __has_builtin(__builtin_amdgcn_exp2f)
  return __builtin_amdgcn_exp2f(x);
#else
  return exp2f(x);
#endif
}

__device__ __forceinline__ void gll16(const void* g, void* l) {
  __builtin_amdgcn_global_load_lds(
      (const __attribute__((address_space(1))) uint32_t*)g,
      (__attribute__((address_space(3))) uint32_t*)l, 16, 0, 0);
}

// ---------------- fused prep: cast hidden + Wq/Wk/Wv transpose + bias + Wo transpose
__global__ __launch_bounds__(256) void prep_k(const float* __restrict__ hidden,
                                              const float* __restrict__ Wq,
                                              const float* __restrict__ Wk,
                                              const float* __restrict__ Wv,
                                              const float* __restrict__ bq,
                                              const float* __restrict__ bk,
                                              const float* __restrict__ bv,
                                              const float* __restrict__ Wo,
                                              u16* __restrict__ Abf,
                                              u16* __restrict__ Wt,
                                              u16* __restrict__ Wot,
                                              float* __restrict__ biasQKV) {
  __shared__ float t[64][65];
  const int bx = blockIdx.x;
  const int tid = threadIdx.x;

  if (bx < 2048) {
    int i = (bx * 256 + tid) * 8;
    float4 a = *(const float4*)(hidden + i);
    float4 b = *(const float4*)(hidden + i + 4);
    short8 o;
    o[0] = (short)f2bf(a.x); o[1] = (short)f2bf(a.y);
    o[2] = (short)f2bf(a.z); o[3] = (short)f2bf(a.w);
    o[4] = (short)f2bf(b.x); o[5] = (short)f2bf(b.y);
    o[6] = (short)f2bf(b.z); o[7] = (short)f2bf(b.w);
    *(short8*)(Abf + i) = o;
    return;
  }

  if (bx < 2816) {
    const int blk = bx - 2048;
    const int by = blk & 15, z = blk >> 4;
    const int grp = z >> 4, h = z & 15;
    const float* src = (grp == 0) ? Wq : (grp == 1) ? Wk : Wv;
    const float* bsrc = (grp == 0) ? bq : (grp == 1) ? bk : bv;
    const float scale = (grp == 0) ? QSCALE : 1.0f;
    u16* dst = Wt + (size_t)grp * 1024 * 1024;
    const float* Sp = src + (size_t)h * 1024 * 64;
    const int r0 = by * 64;
#pragma unroll
    for (int i = 0; i < 4; i++) {
      int r = i * 16 + (tid >> 4), c = (tid & 15) * 4;
      float4 v = *(const float4*)(Sp + (size_t)(r0 + r) * 64 + c);
      t[r][c] = v.x; t[r][c + 1] = v.y; t[r][c + 2] = v.z; t[r][c + 3] = v.w;
    }
    if (by == 0 && tid < 64)
      biasQKV[grp * 1024 + h * 64 + tid] = bsrc[h * 64 + tid] * scale;
    __syncthreads();
#pragma unroll
    for (int i = 0; i < 4; i++) {
      int c = i * 16 + (tid >> 4), r = (tid & 15) * 4;
      ushort4 o;
      o.x = f2bf(t[r][c] * scale);
      o.y = f2bf(t[r + 1][c] * scale);
      o.z = f2bf(t[r + 2][c] * scale);
      o.w = f2bf(t[r + 3][c] * scale);
      *(ushort4*)(dst + (size_t)(h * 64 + c) * 1024 + r0 + r) = o;
    }
    return;
  }

  {
    const int blk = bx - 2816;
    const int c0 = (blk & 15) * 64, r0 = (blk >> 4) * 64;
#pragma unroll
    for (int i = 0; i < 4; i++) {
      int r = i * 16 + (tid >> 4), c = (tid & 15) * 4;
      float4 v = *(const float4*)(Wo + (size_t)(r0 + r) * 1024 + c0 + c);
      t[r][c] = v.x; t[r][c + 1] = v.y; t[r][c + 2] = v.z; t[r][c + 3] = v.w;
    }
    __syncthreads();
#pragma unroll
    for (int i = 0; i < 4; i++) {
      int c = i * 16 + (tid >> 4), r = (tid & 15) * 4;
      ushort4 o;
      o.x = f2bf(t[r][c]);
      o.y = f2bf(t[r + 1][c]);
      o.z = f2bf(t[r + 2][c]);
      o.w = f2bf(t[r + 3][c]);
      *(ushort4*)(Wot + (size_t)(c0 + c) * 1024 + r0 + r) = o;
    }
  }
}

// ---------------- QKV GEMM 128x128, BK=64, XOR-swizzled LDS ------------------
// XCD-aware flat grid (768 = 8 XCDs x (24 n x 4 m)); per-XCD A-band ~1MB.
__global__ __launch_bounds__(256) void gemm_bt_k(const u16* __restrict__ A,
                                                 const u16* __restrict__ B,
                                                 const float* __restrict__ bias,
                                                 u16* __restrict__ Cout,
                                                 int M, int N, int K) {
  __shared__ u16 As[128 * 64];
  __shared__ u16 Bs[128 * 64];
  const int tid = threadIdx.x;
  const int w = tid >> 6, lane = tid & 63;
  const int wm = w >> 1, wn = w & 1;
  const int orig = blockIdx.x;
  const int xcd = orig & 7, idx = orig >> 3;
  const int ni = idx >> 2, mi_ = idx & 3;
  const int m0 = (xcd * 4 + mi_) * 128, n0 = ni * 128;
  const int l15 = lane & 15, quad = lane >> 4;
  const int colr[2] = {(((quad) ^ (l15 & 7)) & 7) * 8,
                       (((4 + quad) ^ (l15 & 7)) & 7) * 8};

  int r_st[4], cs_st[4];
#pragma unroll
  for (int i = 0; i < 4; i++) {
    int idx2 = i * 256 + tid;
    r_st[i] = idx2 >> 3;
    cs_st[i] = ((idx2 & 7) ^ (r_st[i] & 7)) * 8;
  }

  f32x4 acc[4][4];
  const f32x4 zero = {0.f, 0.f, 0.f, 0.f};
#pragma unroll
  for (int i = 0; i < 4; i++)
#pragma unroll
    for (int j = 0; j < 4; j++) acc[i][j] = zero;

  for (int k0 = 0; k0 < K; k0 += 64) {
#pragma unroll
    for (int i = 0; i < 4; i++) {
      gll16(A + (size_t)(m0 + r_st[i]) * K + k0 + cs_st[i], &As[(i * 256 + w * 64) * 8]);
      gll16(B + (size_t)(n0 + r_st[i]) * K + k0 + cs_st[i], &Bs[(i * 256 + w * 64) * 8]);
    }
    __syncthreads();
#pragma unroll
    for (int kk = 0; kk < 2; kk++) {
      short8 af[4], bf[4];
#pragma unroll
      for (int i = 0; i < 4; i++) {
        af[i] = *(const short8*)&As[(wm * 64 + i * 16 + l15) * 64 + colr[kk]];
        bf[i] = *(const short8*)&Bs[(wn * 64 + i * 16 + l15) * 64 + colr[kk]];
      }
#pragma unroll
      for (int mi = 0; mi < 4; mi++)
#pragma unroll
        for (int ni2 = 0; ni2 < 4; ni2++)
          acc[mi][ni2] = __builtin_amdgcn_mfma_f32_16x16x32_bf16(af[mi], bf[ni2], acc[mi][ni2], 0, 0, 0);
    }
    __syncthreads();
  }

  const int cm = m0 + wm * 64, cn = n0 + wn * 64;
#pragma unroll
  for (int ni2 = 0; ni2 < 4; ni2++) {
    int n = cn + ni2 * 16 + l15;
    float bv = bias[n];
#pragma unroll
    for (int mi = 0; mi < 4; mi++) {
#pragma unroll
      for (int r = 0; r < 4; r++) {
        int m = cm + mi * 16 + quad * 4 + r;
        Cout[(size_t)m * N + n] = f2bf(acc[mi][ni2][r] + bv);
      }
    }
  }
}

// ---------------- GEMM 64x128 tile, BK=64 (R10), fp32 out, swizzled ----------
// R10: ported gemm_bt_k's proven BK=64 schedule (granule g^(r&7) staging,
// colr[kk] reads) to the out-projection: barrier-pairs per block 32 -> 16,
// 16 MFMA per barrier-pair (was 8). LDS 24KB, grid 512 = 2 blocks/CU,
// XCD-aware decode (8 x (8n x 8m)).
__global__ __launch_bounds__(256) void gemm_bt64_k(const u16* __restrict__ A,
                                                   const u16* __restrict__ B,
                                                   const float* __restrict__ bias,
                                                   float* __restrict__ Cout,
                                                   int M, int N, int K) {
  __shared__ u16 As[64 * 64];
  __shared__ u16 Bs[128 * 64];
  const int tid = threadIdx.x;
  const int w = tid >> 6, lane = tid & 63;
  const int wm = w >> 1, wn = w & 1;
  const int orig = blockIdx.x;
  const int xcd = orig & 7, idx = orig >> 3;
  const int ni = idx >> 3, mi_ = idx & 7;
  const int m0 = (xcd * 8 + mi_) * 64, n0 = ni * 128;
  const int l15 = lane & 15, quad = lane >> 4;
  const int colr[2] = {(((quad) ^ (l15 & 7)) & 7) * 8,
                       (((4 + quad) ^ (l15 & 7)) & 7) * 8};

  // A: 64x64 = 4096 u16 -> 2 rounds; B: 128x64 = 8192 u16 -> 4 rounds
  int rA[2], cA[2], rB[4], cB[4];
#pragma unroll
  for (int i = 0; i < 2; i++) {
    int idx2 = i * 256 + tid;
    rA[i] = idx2 >> 3;
    cA[i] = ((idx2 & 7) ^ (rA[i] & 7)) * 8;
  }
#pragma unroll
  for (int i = 0; i < 4; i++) {
    int idx2 = i * 256 + tid;
    rB[i] = idx2 >> 3;
    cB[i] = ((idx2 & 7) ^ (rB[i] & 7)) * 8;
  }

  f32x4 acc[2][4];
  const f32x4 zero = {0.f, 0.f, 0.f, 0.f};
#pragma unroll
  for (int i = 0; i < 2; i++)
#pragma unroll
    for (int j = 0; j < 4; j++) acc[i][j] = zero;

  for (int k0 = 0; k0 < K; k0 += 64) {
#pragma unroll
    for (int i = 0; i < 2; i++)
      gll16(A + (size_t)(m0 + rA[i]) * K + k0 + cA[i], &As[(i * 256 + w * 64) * 8]);
#pragma unroll
    for (int i = 0; i < 4; i++)
      gll16(B + (size_t)(n0 + rB[i]) * K + k0 + cB[i], &Bs[(i * 256 + w * 64) * 8]);
    __syncthreads();
#pragma unroll
    for (int kk = 0; kk < 2; kk++) {
      short8 af[2], bf[4];
#pragma unroll
      for (int i = 0; i < 2; i++)
        af[i] = *(const short8*)&As[(wm * 32 + i * 16 + l15) * 64 + colr[kk]];
#pragma unroll
      for (int j = 0; j < 4; j++)
        bf[j] = *(const short8*)&Bs[(wn * 64 + j * 16 + l15) * 64 + colr[kk]];
#pragma unroll
      for (int i = 0; i < 2; i++)
#pragma unroll
        for (int j = 0; j < 4; j++)
          acc[i][j] = __builtin_amdgcn_mfma_f32_16x16x32_bf16(af[i], bf[j], acc[i][j], 0, 0, 0);
    }
    __syncthreads();
  }

  const int cm = m0 + wm * 32, cn = n0 + wn * 64;
#pragma unroll
  for (int j = 0; j < 4; j++) {
    int n = cn + j * 16 + l15;
    float bv = bias[n];
#pragma unroll
    for (int i = 0; i < 2; i++) {
#pragma unroll
      for (int r = 0; r < 4; r++) {
        int m = cm + i * 16 + quad * 4 + r;
        Cout[(size_t)m * N + n] = acc[i][j][r] + bv;
      }
    }
  }
}

// ---------------- V transpose: qkv V region -> Vt [b][h][v][s] bf16 ----------------
__global__ __launch_bounds__(256) void transpose_v_k(const u16* __restrict__ qkv,
                                                     u16* __restrict__ Vt) {
  __shared__ u16 t[64][71];
  const int b = blockIdx.z, h = blockIdx.y, s0 = blockIdx.x * 64;
  const int tid = threadIdx.x;
#pragma unroll
  for (int i = 0; i < 2; i++) {
    int s = i * 32 + (tid >> 3), v = (tid & 7) * 8;
    short8 val = *(const short8*)(qkv + (size_t)(b * S_ + s0 + s) * 3072 + 2048 + h * 64 + v);
#pragma unroll
    for (int j = 0; j < 8; j++) t[s][v + j] = (u16)val[j];
  }
  __syncthreads();
#pragma unroll
  for (int i = 0; i < 2; i++) {
    int v = i * 32 + (tid >> 3), s8 = (tid & 7) * 8;
    short8 o;
#pragma unroll
    for (int j = 0; j < 8; j++) o[j] = (short)t[s8 + j][v];
    *(short8*)(Vt + ((size_t)(b * H_ + h) * 64 + v) * S_ + s0 + s8) = o;
  }
}

// ---------------- flash attention (R8 config, kept: proven ~57us floor) ------
// History: R6 killed LDS P-roundtrip (conflicts->0, no dur change). R7 doubled
// occupancy (no dur change). R8 XCD swizzle: FETCH 69.7->12.3MB (L2-resident)
// but dur -1.3us only. All pipes <50% -> issue/dependency floor under this
// schedule. Do not micro-tweak further; a different sync template would be
// needed for more.
__global__ __launch_bounds__(256, 4) void attn_k(const u16* __restrict__ qkv,
                                                 const u16* __restrict__ Vt,
                                                 u16* __restrict__ ctx) {
  __shared__ u16 Ks[2][64 * 64];
  __shared__ u16 Vs[2][64 * 64];
  const int tid = threadIdx.x;
  const int w = tid >> 6, lane = tid & 63;
  const int wq = w >> 1, wk = w & 1;
  const int l15 = lane & 15, quad = lane >> 4;

  // XCD-aware remap: xcd = orig%8 (dispatch round-robin); each xcd gets a
  // contiguous swz-range of 128 = 4 complete (b,h) groups of 32 q-blocks.
  const int orig = blockIdx.x;
  const int swz = (orig & 7) * 128 + (orig >> 3);
  const int q0 = (swz & 31) * 64;
  const int bh = swz >> 5;
  const int h = bh & 15, b = bh >> 4;

  short8 qf[2][2];
#pragma unroll
  for (int rt = 0; rt < 2; rt++) {
    const u16* qbase = qkv + (size_t)(b * S_ + q0 + wq * 32 + rt * 16 + l15) * 3072 + h * 64;
    qf[rt][0] = *(const short8*)(qbase + quad * 8);
    qf[rt][1] = *(const short8*)(qbase + 32 + quad * 8);
  }

  const int col0 = ((quad ^ (l15 & 7)) & 7) * 8;
  const int col1 = (((4 + quad) ^ (l15 & 7)) & 7) * 8;
  const int colw = wk ? col1 : col0;  // this wave's s-slice of V

  int r_st[2], cs_st[2];
#pragma unroll
  for (int i = 0; i < 2; i++) {
    int idx = i * 256 + tid;
    r_st[i] = idx >> 3;
    cs_st[i] = ((idx & 7) ^ (r_st[i] & 7)) * 8;
  }
  const u16* kp[2];
  const u16* vp[2];
#pragma unroll
  for (int i = 0; i < 2; i++) {
    kp[i] = qkv + (size_t)(b * S_ + r_st[i]) * 3072 + 1024 + h * 64 + cs_st[i];
    vp[i] = Vt + ((size_t)(b * H_ + h) * 64 + r_st[i]) * S_ + cs_st[i];
  }

  const f32x4 zero = {0.f, 0.f, 0.f, 0.f};
  f32x4 o[2][4];
#pragma unroll
  for (int rt = 0; rt < 2; rt++)
#pragma unroll
    for (int i = 0; i < 4; i++) o[rt][i] = zero;
  float lsum[2] = {0.f, 0.f};

  auto stage = [&](int bb, int t) {
#pragma unroll
    for (int i = 0; i < 2; i++) {
      gll16(kp[i] + (size_t)t * 64 * 3072, &Ks[bb][(i * 256 + w * 64) * 8]);
      gll16(vp[i] + t * 64, &Vs[bb][(i * 256 + w * 64) * 8]);
    }
  };

  auto compute = [&](int bb) {
    short8 kf[2][2];
#pragma unroll
    for (int kb = 0; kb < 2; kb++) {
      const int krow = (wk * 32 + kb * 16 + l15) * 64;
      kf[kb][0] = *(const short8*)&Ks[bb][krow + col0];
      kf[kb][1] = *(const short8*)&Ks[bb][krow + col1];
    }
    short8 pf[2];
#pragma unroll
    for (int rt = 0; rt < 2; rt++) {
      uint32_t Sx[2][2];
      __builtin_amdgcn_s_setprio(1);
#pragma unroll
      for (int kb = 0; kb < 2; kb++) {
        f32x4 st = __builtin_amdgcn_mfma_f32_16x16x32_bf16(kf[kb][0], qf[rt][0], zero, 0, 0, 0);
        st = __builtin_amdgcn_mfma_f32_16x16x32_bf16(kf[kb][1], qf[rt][1], st, 0, 0, 0);
        __builtin_amdgcn_s_setprio(0);
        float p0 = fexp2(st[0]), p1 = fexp2(st[1]), p2 = fexp2(st[2]), p3 = fexp2(st[3]);
        lsum[rt] += (p0 + p1) + (p2 + p3);
        Sx[kb][0] = pk_bf16(p0, p1);  // k = kb*16 + quad*4 + {0,1}
        Sx[kb][1] = pk_bf16(p2, p3);  // k = kb*16 + quad*4 + {2,3}
      }
#pragma unroll
      for (int s = 0; s < 2; s++)
        asm volatile("v_permlane32_swap_b32 %0, %1" : "+v"(Sx[0][s]), "+v"(Sx[1][s]));
#pragma unroll
      for (int s = 0; s < 2; s++)
        asm volatile("v_permlane16_swap_b32 %0, %1" : "+v"(Sx[0][s]), "+v"(Sx[1][s]));
      union { uint32_t u[4]; short8 s8; } cv;
      cv.u[0] = Sx[0][0]; cv.u[1] = Sx[0][1];
      cv.u[2] = Sx[1][0]; cv.u[3] = Sx[1][1];
      pf[rt] = cv.s8;
    }
    __builtin_amdgcn_s_setprio(1);
#pragma unroll
    for (int vi = 0; vi < 4; vi++) {
      short8 vf = *(const short8*)&Vs[bb][(vi * 16 + l15) * 64 + colw];
      o[0][vi] = __builtin_amdgcn_mfma_f32_16x16x32_bf16(vf, pf[0], o[0][vi], 0, 0, 0);
      o[1][vi] = __builtin_amdgcn_mfma_f32_16x16x32_bf16(vf, pf[1], o[1][vi], 0, 0, 0);
    }
    __builtin_amdgcn_s_setprio(0);
  };

  stage(0, 0);
  for (int t = 0; t < 31; t++) {
    __syncthreads();
    stage((t + 1) & 1, t + 1);
    compute(t & 1);
  }
  __syncthreads();
  compute(1);

  // ---- cross-wave (wk) reduction of O and lsum through freed LDS ----
  float ls[2];
#pragma unroll
  for (int rt = 0; rt < 2; rt++) {
    float l = lsum[rt];
    l += __shfl_xor(l, 16);
    l += __shfl_xor(l, 32);
    ls[rt] = l;
  }
  __syncthreads();  // all compute reads of Ks/Vs done before reuse
  float* red = (float*)&Ks[0][0];   // 16 KB: 2 wq-waves x 8 KB
  float* redl = (float*)&Vs[0][0];  // 1 KB
  if (wk == 1) {
#pragma unroll
    for (int rt = 0; rt < 2; rt++) {
#pragma unroll
      for (int vi = 0; vi < 4; vi++)
        *(f32x4*)(red + wq * 2048 + (rt * 4 + vi) * 256 + lane * 4) = o[rt][vi];
      redl[wq * 128 + rt * 64 + lane] = ls[rt];
    }
  }
  __syncthreads();
  if (wk == 0) {
#pragma unroll
    for (int rt = 0; rt < 2; rt++) {
      const float tot = ls[rt] + redl[wq * 128 + rt * 64 + lane];
      const float inv = 1.f / tot;
      u16* cbase = ctx + (size_t)(b * S_ + q0 + wq * 32 + rt * 16 + l15) * 1024 + h * 64;
#pragma unroll
      for (int vi = 0; vi < 4; vi++) {
        f32x4 p = *(f32x4*)(red + wq * 2048 + (rt * 4 + vi) * 256 + lane * 4);
        f32x4 s = o[rt][vi] + p;
        ushort4 pk;
        pk.x = f2bf(s[0] * inv);
        pk.y = f2bf(s[1] * inv);
        pk.z = f2bf(s[2] * inv);
        pk.w = f2bf(s[3] * inv);
        *(ushort4*)(cbase + vi * 16 + quad * 4) = pk;
      }
    }
  }
}

extern "C" void kernel_launch(void* const* d_in, const int* in_sizes, int n_in,
                              void* d_out, int out_size, void* d_ws, size_t ws_size,
                              hipStream_t stream) {
  const float* hidden = (const float*)d_in[0];
  const float* Wq = (const float*)d_in[1];
  const float* bq = (const float*)d_in[2];
  const float* Wk = (const float*)d_in[3];
  const float* bk = (const float*)d_in[4];
  const float* Wv = (const float*)d_in[5];
  const float* bv = (const float*)d_in[6];
  const float* Wo = (const float*)d_in[7];
  const float* bo = (const float*)d_in[8];
  float* out = (float*)d_out;

  char* ws = (char*)d_ws;
  u16* Abf = (u16*)(ws + 0);                 // 4096x1024 bf16   (8,388,608)
  u16* Wt = (u16*)(ws + 8388608);            // 3072x1024 bf16   (6,291,456)
  u16* Wot = (u16*)(ws + 14680064);          // 1024x1024 bf16   (2,097,152)
  float* biasQKV = (float*)(ws + 16777216);  // 3072 fp32        (12,288 padded)
  u16* qkv = (u16*)(ws + 16789504);          // 4096x3072 bf16   (25,165,824)
  u16* Vt = (u16*)(ws + 41955328);           // [b][h][64][2048] (8,388,608)
  u16* ctx = (u16*)(ws + 50343936);          // 4096x1024 bf16   (8,388,608)

  // fused prep: cast + Wq/Wk/Wv transpose + bias + Wo transpose
  prep_k<<<3072, 256, 0, stream>>>(hidden, Wq, Wk, Wv, bq, bk, bv, Wo,
                                   Abf, Wt, Wot, biasQKV);

  // QKV projection: [4096,1024] x [3072,1024]^T -> [4096,3072] bf16 (BK=64)
  // flat grid, XCD-aware decode inside
  gemm_bt_k<<<dim3(768), 256, 0, stream>>>(Abf, Wt, biasQKV, qkv, 4096, 3072, 1024);

  // V transpose for PV A-operand
  transpose_v_k<<<dim3(32, 16, 2), 256, 0, stream>>>(qkv, Vt);

  // flash attention -> ctx [4096, 1024] bf16  (flat grid, XCD-aware swizzle)
  attn_k<<<dim3(1024), 256, 0, stream>>>(qkv, Vt, ctx);

  // output projection: [4096,1024] x [1024,1024]^T + bo -> fp32 out (BK=64)
  gemm_bt64_k<<<dim3(512), 256, 0, stream>>>(ctx, Wot, bo, out, 4096, 1024, 1024);
}

// Round 7
// 199.489 us; speedup vs baseline: 1.0613x; 1.0124x over previous
//
#include <hip/hip_runtime.h>
#include <hip/hip_bf16.h>
#include <stdint.h>

typedef unsigned short u16;
typedef __attribute__((ext_vector_type(8))) short short8;
typedef __attribute__((ext_vector_type(4))) float f32x4;

#define B_ 2
#define S_ 2048
#define D_ 1024
#define H_ 16
#define DK_ 64
// scale folded into Q: (1/sqrt(DK)) * log2(e)  -> softmax done with exp2
#define QSCALE 0.18033688011112042f

__device__ __forceinline__ u16 f2bf(float f) {
  union { float f; uint32_t u; } c; c.f = f;
  uint32_t u = c.u;
  u += 0x7fffu + ((u >> 16) & 1u);
  return (u16)(u >> 16);
}

__device__ __forceinline__ uint32_t pk_bf16(float a, float b) {
  __hip_bfloat162 h = __float22bfloat162_rn(float2{a, b});
  union { __hip_bfloat162 h; uint32_t u; } c; c.h = h;
  return c.u;
}

__device__ __forceinline__ float fexp2(float x) {
#if __has_builtin(__builtin_amdgcn_exp2f)
  return __builtin_amdgcn_exp2f(x);
#else
  return exp2f(x);
#endif
}

__device__ __forceinline__ void gll16(const void* g, void* l) {
  __builtin_amdgcn_global_load_lds(
      (const __attribute__((address_space(1))) uint32_t*)g,
      (__attribute__((address_space(3))) uint32_t*)l, 16, 0, 0);
}

// ---------------- fused prep: cast hidden + Wq/Wk/Wv transpose + bias + Wo transpose
__global__ __launch_bounds__(256) void prep_k(const float* __restrict__ hidden,
                                              const float* __restrict__ Wq,
                                              const float* __restrict__ Wk,
                                              const float* __restrict__ Wv,
                                              const float* __restrict__ bq,
                                              const float* __restrict__ bk,
                                              const float* __restrict__ bv,
                                              const float* __restrict__ Wo,
                                              u16* __restrict__ Abf,
                                              u16* __restrict__ Wt,
                                              u16* __restrict__ Wot,
                                              float* __restrict__ biasQKV) {
  __shared__ float t[64][65];
  const int bx = blockIdx.x;
  const int tid = threadIdx.x;

  if (bx < 2048) {
    int i = (bx * 256 + tid) * 8;
    float4 a = *(const float4*)(hidden + i);
    float4 b = *(const float4*)(hidden + i + 4);
    short8 o;
    o[0] = (short)f2bf(a.x); o[1] = (short)f2bf(a.y);
    o[2] = (short)f2bf(a.z); o[3] = (short)f2bf(a.w);
    o[4] = (short)f2bf(b.x); o[5] = (short)f2bf(b.y);
    o[6] = (short)f2bf(b.z); o[7] = (short)f2bf(b.w);
    *(short8*)(Abf + i) = o;
    return;
  }

  if (bx < 2816) {
    const int blk = bx - 2048;
    const int by = blk & 15, z = blk >> 4;
    const int grp = z >> 4, h = z & 15;
    const float* src = (grp == 0) ? Wq : (grp == 1) ? Wk : Wv;
    const float* bsrc = (grp == 0) ? bq : (grp == 1) ? bk : bv;
    const float scale = (grp == 0) ? QSCALE : 1.0f;
    u16* dst = Wt + (size_t)grp * 1024 * 1024;
    const float* Sp = src + (size_t)h * 1024 * 64;
    const int r0 = by * 64;
#pragma unroll
    for (int i = 0; i < 4; i++) {
      int r = i * 16 + (tid >> 4), c = (tid & 15) * 4;
      float4 v = *(const float4*)(Sp + (size_t)(r0 + r) * 64 + c);
      t[r][c] = v.x; t[r][c + 1] = v.y; t[r][c + 2] = v.z; t[r][c + 3] = v.w;
    }
    if (by == 0 && tid < 64)
      biasQKV[grp * 1024 + h * 64 + tid] = bsrc[h * 64 + tid] * scale;
    __syncthreads();
#pragma unroll
    for (int i = 0; i < 4; i++) {
      int c = i * 16 + (tid >> 4), r = (tid & 15) * 4;
      ushort4 o;
      o.x = f2bf(t[r][c] * scale);
      o.y = f2bf(t[r + 1][c] * scale);
      o.z = f2bf(t[r + 2][c] * scale);
      o.w = f2bf(t[r + 3][c] * scale);
      *(ushort4*)(dst + (size_t)(h * 64 + c) * 1024 + r0 + r) = o;
    }
    return;
  }

  {
    const int blk = bx - 2816;
    const int c0 = (blk & 15) * 64, r0 = (blk >> 4) * 64;
#pragma unroll
    for (int i = 0; i < 4; i++) {
      int r = i * 16 + (tid >> 4), c = (tid & 15) * 4;
      float4 v = *(const float4*)(Wo + (size_t)(r0 + r) * 1024 + c0 + c);
      t[r][c] = v.x; t[r][c + 1] = v.y; t[r][c + 2] = v.z; t[r][c + 3] = v.w;
    }
    __syncthreads();
#pragma unroll
    for (int i = 0; i < 4; i++) {
      int c = i * 16 + (tid >> 4), r = (tid & 15) * 4;
      ushort4 o;
      o.x = f2bf(t[r][c]);
      o.y = f2bf(t[r + 1][c]);
      o.z = f2bf(t[r + 2][c]);
      o.w = f2bf(t[r + 3][c]);
      *(ushort4*)(Wot + (size_t)(c0 + c) * 1024 + r0 + r) = o;
    }
  }
}

// ---------------- QKV GEMM 128x128, BK=64, XOR-swizzled LDS ------------------
// XCD-aware flat grid (768 = 8 XCDs x (24 n x 4 m)); per-XCD A-band ~1MB.
// R11: V-region blocks (n0 >= 2048) write their output TRANSPOSED directly to
// Vt [b][h][v][s] (per-lane acc quad = 4 consecutive m = 4 consecutive s ->
// contiguous ushort4; 4 quads -> 32B segments). Replaces the separate
// transpose_v_k kernel and the 16MB qkv-V round-trip. Q/K blocks unchanged.
__global__ __launch_bounds__(256) void gemm_bt_k(const u16* __restrict__ A,
                                                 const u16* __restrict__ B,
                                                 const float* __restrict__ bias,
                                                 u16* __restrict__ Cout,
                                                 u16* __restrict__ Vt,
                                                 int M, int N, int K) {
  __shared__ u16 As[128 * 64];
  __shared__ u16 Bs[128 * 64];
  const int tid = threadIdx.x;
  const int w = tid >> 6, lane = tid & 63;
  const int wm = w >> 1, wn = w & 1;
  const int orig = blockIdx.x;
  const int xcd = orig & 7, idx = orig >> 3;
  const int ni = idx >> 2, mi_ = idx & 3;
  const int m0 = (xcd * 4 + mi_) * 128, n0 = ni * 128;
  const int l15 = lane & 15, quad = lane >> 4;
  const int colr[2] = {(((quad) ^ (l15 & 7)) & 7) * 8,
                       (((4 + quad) ^ (l15 & 7)) & 7) * 8};

  int r_st[4], cs_st[4];
#pragma unroll
  for (int i = 0; i < 4; i++) {
    int idx2 = i * 256 + tid;
    r_st[i] = idx2 >> 3;
    cs_st[i] = ((idx2 & 7) ^ (r_st[i] & 7)) * 8;
  }

  f32x4 acc[4][4];
  const f32x4 zero = {0.f, 0.f, 0.f, 0.f};
#pragma unroll
  for (int i = 0; i < 4; i++)
#pragma unroll
    for (int j = 0; j < 4; j++) acc[i][j] = zero;

  for (int k0 = 0; k0 < K; k0 += 64) {
#pragma unroll
    for (int i = 0; i < 4; i++) {
      gll16(A + (size_t)(m0 + r_st[i]) * K + k0 + cs_st[i], &As[(i * 256 + w * 64) * 8]);
      gll16(B + (size_t)(n0 + r_st[i]) * K + k0 + cs_st[i], &Bs[(i * 256 + w * 64) * 8]);
    }
    __syncthreads();
#pragma unroll
    for (int kk = 0; kk < 2; kk++) {
      short8 af[4], bf[4];
#pragma unroll
      for (int i = 0; i < 4; i++) {
        af[i] = *(const short8*)&As[(wm * 64 + i * 16 + l15) * 64 + colr[kk]];
        bf[i] = *(const short8*)&Bs[(wn * 64 + i * 16 + l15) * 64 + colr[kk]];
      }
#pragma unroll
      for (int mi = 0; mi < 4; mi++)
#pragma unroll
        for (int ni2 = 0; ni2 < 4; ni2++)
          acc[mi][ni2] = __builtin_amdgcn_mfma_f32_16x16x32_bf16(af[mi], bf[ni2], acc[mi][ni2], 0, 0, 0);
    }
    __syncthreads();
  }

  const int cm = m0 + wm * 64, cn = n0 + wn * 64;
  if (n0 < 2048) {
    // Q/K region: row-major write into qkv
#pragma unroll
    for (int ni2 = 0; ni2 < 4; ni2++) {
      int n = cn + ni2 * 16 + l15;
      float bv = bias[n];
#pragma unroll
      for (int mi = 0; mi < 4; mi++) {
#pragma unroll
        for (int r = 0; r < 4; r++) {
          int m = cm + mi * 16 + quad * 4 + r;
          Cout[(size_t)m * N + n] = f2bf(acc[mi][ni2][r] + bv);
        }
      }
    }
  } else {
    // V region: write transposed directly to Vt [b][h][v][s]
    const int bidx = m0 >> 11;        // batch (block-uniform; 2048 % 128 == 0)
    const int sbase = (cm & 2047) + quad * 4;
#pragma unroll
    for (int ni2 = 0; ni2 < 4; ni2++) {
      const int n = cn + ni2 * 16 + l15;
      const int vg = n - 2048;        // h*64 + v
      const float bv = bias[n];
      u16* vbase = Vt + (size_t)(bidx * 1024 + vg) * 2048 + sbase;
#pragma unroll
      for (int mi = 0; mi < 4; mi++) {
        ushort4 pk;
        pk.x = f2bf(acc[mi][ni2][0] + bv);
        pk.y = f2bf(acc[mi][ni2][1] + bv);
        pk.z = f2bf(acc[mi][ni2][2] + bv);
        pk.w = f2bf(acc[mi][ni2][3] + bv);
        *(ushort4*)(vbase + mi * 16) = pk;
      }
    }
  }
}

// ---------------- GEMM 64x128 tile, BK=64, fp32 out, swizzled ----------------
// XCD-aware flat grid (512 = 8 x (8n x 8m)); BK=64 schedule ported from
// gemm_bt_k (R10): 16 barrier-pairs, 16 MFMA per pair. LDS 24KB.
__global__ __launch_bounds__(256) void gemm_bt64_k(const u16* __restrict__ A,
                                                   const u16* __restrict__ B,
                                                   const float* __restrict__ bias,
                                                   float* __restrict__ Cout,
                                                   int M, int N, int K) {
  __shared__ u16 As[64 * 64];
  __shared__ u16 Bs[128 * 64];
  const int tid = threadIdx.x;
  const int w = tid >> 6, lane = tid & 63;
  const int wm = w >> 1, wn = w & 1;
  const int orig = blockIdx.x;
  const int xcd = orig & 7, idx = orig >> 3;
  const int ni = idx >> 3, mi_ = idx & 7;
  const int m0 = (xcd * 8 + mi_) * 64, n0 = ni * 128;
  const int l15 = lane & 15, quad = lane >> 4;
  const int colr[2] = {(((quad) ^ (l15 & 7)) & 7) * 8,
                       (((4 + quad) ^ (l15 & 7)) & 7) * 8};

  // A: 64x64 = 4096 u16 -> 2 rounds; B: 128x64 = 8192 u16 -> 4 rounds
  int rA[2], cA[2], rB[4], cB[4];
#pragma unroll
  for (int i = 0; i < 2; i++) {
    int idx2 = i * 256 + tid;
    rA[i] = idx2 >> 3;
    cA[i] = ((idx2 & 7) ^ (rA[i] & 7)) * 8;
  }
#pragma unroll
  for (int i = 0; i < 4; i++) {
    int idx2 = i * 256 + tid;
    rB[i] = idx2 >> 3;
    cB[i] = ((idx2 & 7) ^ (rB[i] & 7)) * 8;
  }

  f32x4 acc[2][4];
  const f32x4 zero = {0.f, 0.f, 0.f, 0.f};
#pragma unroll
  for (int i = 0; i < 2; i++)
#pragma unroll
    for (int j = 0; j < 4; j++) acc[i][j] = zero;

  for (int k0 = 0; k0 < K; k0 += 64) {
#pragma unroll
    for (int i = 0; i < 2; i++)
      gll16(A + (size_t)(m0 + rA[i]) * K + k0 + cA[i], &As[(i * 256 + w * 64) * 8]);
#pragma unroll
    for (int i = 0; i < 4; i++)
      gll16(B + (size_t)(n0 + rB[i]) * K + k0 + cB[i], &Bs[(i * 256 + w * 64) * 8]);
    __syncthreads();
#pragma unroll
    for (int kk = 0; kk < 2; kk++) {
      short8 af[2], bf[4];
#pragma unroll
      for (int i = 0; i < 2; i++)
        af[i] = *(const short8*)&As[(wm * 32 + i * 16 + l15) * 64 + colr[kk]];
#pragma unroll
      for (int j = 0; j < 4; j++)
        bf[j] = *(const short8*)&Bs[(wn * 64 + j * 16 + l15) * 64 + colr[kk]];
#pragma unroll
      for (int i = 0; i < 2; i++)
#pragma unroll
        for (int j = 0; j < 4; j++)
          acc[i][j] = __builtin_amdgcn_mfma_f32_16x16x32_bf16(af[i], bf[j], acc[i][j], 0, 0, 0);
    }
    __syncthreads();
  }

  const int cm = m0 + wm * 32, cn = n0 + wn * 64;
#pragma unroll
  for (int j = 0; j < 4; j++) {
    int n = cn + j * 16 + l15;
    float bv = bias[n];
#pragma unroll
    for (int i = 0; i < 2; i++) {
#pragma unroll
      for (int r = 0; r < 4; r++) {
        int m = cm + i * 16 + quad * 4 + r;
        Cout[(size_t)m * N + n] = acc[i][j][r] + bv;
      }
    }
  }
}

// ---------------- flash attention (R8 config, kept: proven ~57us floor) ------
// History: R6 killed LDS P-roundtrip (conflicts->0, no dur change). R7 doubled
// occupancy (no dur change). R8 XCD swizzle: FETCH 69.7->12.3MB (L2-resident)
// but dur -1.3us only. All pipes <50% -> issue/dependency floor under this
// schedule. Do not micro-tweak further; a different sync template would be
// needed for more.
__global__ __launch_bounds__(256, 4) void attn_k(const u16* __restrict__ qkv,
                                                 const u16* __restrict__ Vt,
                                                 u16* __restrict__ ctx) {
  __shared__ u16 Ks[2][64 * 64];
  __shared__ u16 Vs[2][64 * 64];
  const int tid = threadIdx.x;
  const int w = tid >> 6, lane = tid & 63;
  const int wq = w >> 1, wk = w & 1;
  const int l15 = lane & 15, quad = lane >> 4;

  // XCD-aware remap: xcd = orig%8 (dispatch round-robin); each xcd gets a
  // contiguous swz-range of 128 = 4 complete (b,h) groups of 32 q-blocks.
  const int orig = blockIdx.x;
  const int swz = (orig & 7) * 128 + (orig >> 3);
  const int q0 = (swz & 31) * 64;
  const int bh = swz >> 5;
  const int h = bh & 15, b = bh >> 4;

  short8 qf[2][2];
#pragma unroll
  for (int rt = 0; rt < 2; rt++) {
    const u16* qbase = qkv + (size_t)(b * S_ + q0 + wq * 32 + rt * 16 + l15) * 3072 + h * 64;
    qf[rt][0] = *(const short8*)(qbase + quad * 8);
    qf[rt][1] = *(const short8*)(qbase + 32 + quad * 8);
  }

  const int col0 = ((quad ^ (l15 & 7)) & 7) * 8;
  const int col1 = (((4 + quad) ^ (l15 & 7)) & 7) * 8;
  const int colw = wk ? col1 : col0;  // this wave's s-slice of V

  int r_st[2], cs_st[2];
#pragma unroll
  for (int i = 0; i < 2; i++) {
    int idx = i * 256 + tid;
    r_st[i] = idx >> 3;
    cs_st[i] = ((idx & 7) ^ (r_st[i] & 7)) * 8;
  }
  const u16* kp[2];
  const u16* vp[2];
#pragma unroll
  for (int i = 0; i < 2; i++) {
    kp[i] = qkv + (size_t)(b * S_ + r_st[i]) * 3072 + 1024 + h * 64 + cs_st[i];
    vp[i] = Vt + ((size_t)(b * H_ + h) * 64 + r_st[i]) * S_ + cs_st[i];
  }

  const f32x4 zero = {0.f, 0.f, 0.f, 0.f};
  f32x4 o[2][4];
#pragma unroll
  for (int rt = 0; rt < 2; rt++)
#pragma unroll
    for (int i = 0; i < 4; i++) o[rt][i] = zero;
  float lsum[2] = {0.f, 0.f};

  auto stage = [&](int bb, int t) {
#pragma unroll
    for (int i = 0; i < 2; i++) {
      gll16(kp[i] + (size_t)t * 64 * 3072, &Ks[bb][(i * 256 + w * 64) * 8]);
      gll16(vp[i] + t * 64, &Vs[bb][(i * 256 + w * 64) * 8]);
    }
  };

  auto compute = [&](int bb) {
    short8 kf[2][2];
#pragma unroll
    for (int kb = 0; kb < 2; kb++) {
      const int krow = (wk * 32 + kb * 16 + l15) * 64;
      kf[kb][0] = *(const short8*)&Ks[bb][krow + col0];
      kf[kb][1] = *(const short8*)&Ks[bb][krow + col1];
    }
    short8 pf[2];
#pragma unroll
    for (int rt = 0; rt < 2; rt++) {
      uint32_t Sx[2][2];
      __builtin_amdgcn_s_setprio(1);
#pragma unroll
      for (int kb = 0; kb < 2; kb++) {
        f32x4 st = __builtin_amdgcn_mfma_f32_16x16x32_bf16(kf[kb][0], qf[rt][0], zero, 0, 0, 0);
        st = __builtin_amdgcn_mfma_f32_16x16x32_bf16(kf[kb][1], qf[rt][1], st, 0, 0, 0);
        __builtin_amdgcn_s_setprio(0);
        float p0 = fexp2(st[0]), p1 = fexp2(st[1]), p2 = fexp2(st[2]), p3 = fexp2(st[3]);
        lsum[rt] += (p0 + p1) + (p2 + p3);
        Sx[kb][0] = pk_bf16(p0, p1);  // k = kb*16 + quad*4 + {0,1}
        Sx[kb][1] = pk_bf16(p2, p3);  // k = kb*16 + quad*4 + {2,3}
      }
#pragma unroll
      for (int s = 0; s < 2; s++)
        asm volatile("v_permlane32_swap_b32 %0, %1" : "+v"(Sx[0][s]), "+v"(Sx[1][s]));
#pragma unroll
      for (int s = 0; s < 2; s++)
        asm volatile("v_permlane16_swap_b32 %0, %1" : "+v"(Sx[0][s]), "+v"(Sx[1][s]));
      union { uint32_t u[4]; short8 s8; } cv;
      cv.u[0] = Sx[0][0]; cv.u[1] = Sx[0][1];
      cv.u[2] = Sx[1][0]; cv.u[3] = Sx[1][1];
      pf[rt] = cv.s8;
    }
    __builtin_amdgcn_s_setprio(1);
#pragma unroll
    for (int vi = 0; vi < 4; vi++) {
      short8 vf = *(const short8*)&Vs[bb][(vi * 16 + l15) * 64 + colw];
      o[0][vi] = __builtin_amdgcn_mfma_f32_16x16x32_bf16(vf, pf[0], o[0][vi], 0, 0, 0);
      o[1][vi] = __builtin_amdgcn_mfma_f32_16x16x32_bf16(vf, pf[1], o[1][vi], 0, 0, 0);
    }
    __builtin_amdgcn_s_setprio(0);
  };

  stage(0, 0);
  for (int t = 0; t < 31; t++) {
    __syncthreads();
    stage((t + 1) & 1, t + 1);
    compute(t & 1);
  }
  __syncthreads();
  compute(1);

  // ---- cross-wave (wk) reduction of O and lsum through freed LDS ----
  float ls[2];
#pragma unroll
  for (int rt = 0; rt < 2; rt++) {
    float l = lsum[rt];
    l += __shfl_xor(l, 16);
    l += __shfl_xor(l, 32);
    ls[rt] = l;
  }
  __syncthreads();  // all compute reads of Ks/Vs done before reuse
  float* red = (float*)&Ks[0][0];   // 16 KB: 2 wq-waves x 8 KB
  float* redl = (float*)&Vs[0][0];  // 1 KB
  if (wk == 1) {
#pragma unroll
    for (int rt = 0; rt < 2; rt++) {
#pragma unroll
      for (int vi = 0; vi < 4; vi++)
        *(f32x4*)(red + wq * 2048 + (rt * 4 + vi) * 256 + lane * 4) = o[rt][vi];
      redl[wq * 128 + rt * 64 + lane] = ls[rt];
    }
  }
  __syncthreads();
  if (wk == 0) {
#pragma unroll
    for (int rt = 0; rt < 2; rt++) {
      const float tot = ls[rt] + redl[wq * 128 + rt * 64 + lane];
      const float inv = 1.f / tot;
      u16* cbase = ctx + (size_t)(b * S_ + q0 + wq * 32 + rt * 16 + l15) * 1024 + h * 64;
#pragma unroll
      for (int vi = 0; vi < 4; vi++) {
        f32x4 p = *(f32x4*)(red + wq * 2048 + (rt * 4 + vi) * 256 + lane * 4);
        f32x4 s = o[rt][vi] + p;
        ushort4 pk;
        pk.x = f2bf(s[0] * inv);
        pk.y = f2bf(s[1] * inv);
        pk.z = f2bf(s[2] * inv);
        pk.w = f2bf(s[3] * inv);
        *(ushort4*)(cbase + vi * 16 + quad * 4) = pk;
      }
    }
  }
}

extern "C" void kernel_launch(void* const* d_in, const int* in_sizes, int n_in,
                              void* d_out, int out_size, void* d_ws, size_t ws_size,
                              hipStream_t stream) {
  const float* hidden = (const float*)d_in[0];
  const float* Wq = (const float*)d_in[1];
  const float* bq = (const float*)d_in[2];
  const float* Wk = (const float*)d_in[3];
  const float* bk = (const float*)d_in[4];
  const float* Wv = (const float*)d_in[5];
  const float* bv = (const float*)d_in[6];
  const float* Wo = (const float*)d_in[7];
  const float* bo = (const float*)d_in[8];
  float* out = (float*)d_out;

  char* ws = (char*)d_ws;
  u16* Abf = (u16*)(ws + 0);                 // 4096x1024 bf16   (8,388,608)
  u16* Wt = (u16*)(ws + 8388608);            // 3072x1024 bf16   (6,291,456)
  u16* Wot = (u16*)(ws + 14680064);          // 1024x1024 bf16   (2,097,152)
  float* biasQKV = (float*)(ws + 16777216);  // 3072 fp32        (12,288 padded)
  u16* qkv = (u16*)(ws + 16789504);          // 4096x3072 bf16   (25,165,824; V third unused)
  u16* Vt = (u16*)(ws + 41955328);           // [b][h][64][2048] (8,388,608)
  u16* ctx = (u16*)(ws + 50343936);          // 4096x1024 bf16   (8,388,608)

  // fused prep: cast + Wq/Wk/Wv transpose + bias + Wo transpose
  prep_k<<<3072, 256, 0, stream>>>(hidden, Wq, Wk, Wv, bq, bk, bv, Wo,
                                   Abf, Wt, Wot, biasQKV);

  // QKV projection: [4096,1024] x [3072,1024]^T -> qkv (Q,K) + Vt (V, fused
  // transpose). Flat grid, XCD-aware decode inside.
  gemm_bt_k<<<dim3(768), 256, 0, stream>>>(Abf, Wt, biasQKV, qkv, Vt, 4096, 3072, 1024);

  // flash attention -> ctx [4096, 1024] bf16  (flat grid, XCD-aware swizzle)
  attn_k<<<dim3(1024), 256, 0, stream>>>(qkv, Vt, ctx);

  // output projection: [4096,1024] x [1024,1024]^T + bo -> fp32 out (BK=64)
  gemm_bt64_k<<<dim3(512), 256, 0, stream>>>(ctx, Wot, bo, out, 4096, 1024, 1024);
}

// Round 8
// 198.843 us; speedup vs baseline: 1.0648x; 1.0032x over previous
//
#include <hip/hip_runtime.h>
#include <hip/hip_bf16.h>
#include <stdint.h>

typedef unsigned short u16;
typedef __attribute__((ext_vector_type(8))) short short8;
typedef __attribute__((ext_vector_type(4))) float f32x4;

#define B_ 2
#define S_ 2048
#define D_ 1024
#define H_ 16
#define DK_ 64
// scale folded into Q: (1/sqrt(DK)) * log2(e)  -> softmax done with exp2
#define QSCALE 0.18033688011112042f

__device__ __forceinline__ u16 f2bf(float f) {
  union { float f; uint32_t u; } c; c.f = f;
  uint32_t u = c.u;
  u += 0x7fffu + ((u >> 16) & 1u);
  return (u16)(u >> 16);
}

__device__ __forceinline__ uint32_t pk_bf16(float a, float b) {
  __hip_bfloat162 h = __float22bfloat162_rn(float2{a, b});
  union { __hip_bfloat162 h; uint32_t u; } c; c.h = h;
  return c.u;
}

__device__ __forceinline__ float fexp2(float x) {
#if __has_builtin(__builtin_amdgcn_exp2f)
  return __builtin_amdgcn_exp2f(x);
#else
  return exp2f(x);
#endif
}

__device__ __forceinline__ void gll16(const void* g, void* l) {
  __builtin_amdgcn_global_load_lds(
      (const __attribute__((address_space(1))) uint32_t*)g,
      (__attribute__((address_space(3))) uint32_t*)l, 16, 0, 0);
}

// ---------------- fused prep: cast hidden + Wq/Wk/Wv transpose + bias + Wo transpose
__global__ __launch_bounds__(256) void prep_k(const float* __restrict__ hidden,
                                              const float* __restrict__ Wq,
                                              const float* __restrict__ Wk,
                                              const float* __restrict__ Wv,
                                              const float* __restrict__ bq,
                                              const float* __restrict__ bk,
                                              const float* __restrict__ bv,
                                              const float* __restrict__ Wo,
                                              u16* __restrict__ Abf,
                                              u16* __restrict__ Wt,
                                              u16* __restrict__ Wot,
                                              float* __restrict__ biasQKV) {
  __shared__ float t[64][65];
  const int bx = blockIdx.x;
  const int tid = threadIdx.x;

  if (bx < 2048) {
    int i = (bx * 256 + tid) * 8;
    float4 a = *(const float4*)(hidden + i);
    float4 b = *(const float4*)(hidden + i + 4);
    short8 o;
    o[0] = (short)f2bf(a.x); o[1] = (short)f2bf(a.y);
    o[2] = (short)f2bf(a.z); o[3] = (short)f2bf(a.w);
    o[4] = (short)f2bf(b.x); o[5] = (short)f2bf(b.y);
    o[6] = (short)f2bf(b.z); o[7] = (short)f2bf(b.w);
    *(short8*)(Abf + i) = o;
    return;
  }

  if (bx < 2816) {
    const int blk = bx - 2048;
    const int by = blk & 15, z = blk >> 4;
    const int grp = z >> 4, h = z & 15;
    const float* src = (grp == 0) ? Wq : (grp == 1) ? Wk : Wv;
    const float* bsrc = (grp == 0) ? bq : (grp == 1) ? bk : bv;
    const float scale = (grp == 0) ? QSCALE : 1.0f;
    u16* dst = Wt + (size_t)grp * 1024 * 1024;
    const float* Sp = src + (size_t)h * 1024 * 64;
    const int r0 = by * 64;
#pragma unroll
    for (int i = 0; i < 4; i++) {
      int r = i * 16 + (tid >> 4), c = (tid & 15) * 4;
      float4 v = *(const float4*)(Sp + (size_t)(r0 + r) * 64 + c);
      t[r][c] = v.x; t[r][c + 1] = v.y; t[r][c + 2] = v.z; t[r][c + 3] = v.w;
    }
    if (by == 0 && tid < 64)
      biasQKV[grp * 1024 + h * 64 + tid] = bsrc[h * 64 + tid] * scale;
    __syncthreads();
#pragma unroll
    for (int i = 0; i < 4; i++) {
      int c = i * 16 + (tid >> 4), r = (tid & 15) * 4;
      ushort4 o;
      o.x = f2bf(t[r][c] * scale);
      o.y = f2bf(t[r + 1][c] * scale);
      o.z = f2bf(t[r + 2][c] * scale);
      o.w = f2bf(t[r + 3][c] * scale);
      *(ushort4*)(dst + (size_t)(h * 64 + c) * 1024 + r0 + r) = o;
    }
    return;
  }

  {
    const int blk = bx - 2816;
    const int c0 = (blk & 15) * 64, r0 = (blk >> 4) * 64;
#pragma unroll
    for (int i = 0; i < 4; i++) {
      int r = i * 16 + (tid >> 4), c = (tid & 15) * 4;
      float4 v = *(const float4*)(Wo + (size_t)(r0 + r) * 1024 + c0 + c);
      t[r][c] = v.x; t[r][c + 1] = v.y; t[r][c + 2] = v.z; t[r][c + 3] = v.w;
    }
    __syncthreads();
#pragma unroll
    for (int i = 0; i < 4; i++) {
      int c = i * 16 + (tid >> 4), r = (tid & 15) * 4;
      ushort4 o;
      o.x = f2bf(t[r][c]);
      o.y = f2bf(t[r + 1][c]);
      o.z = f2bf(t[r + 2][c]);
      o.w = f2bf(t[r + 3][c]);
      *(ushort4*)(Wot + (size_t)(c0 + c) * 1024 + r0 + r) = o;
    }
  }
}

// ---------------- QKV GEMM 128x128, BK=64, XOR-swizzled LDS ------------------
// XCD-aware flat grid (768 = 8 XCDs x (24 n x 4 m)); per-XCD A-band ~1MB.
// V-region blocks (n0 >= 2048) write output transposed directly to Vt.
// Kept single-buffered: dbuf would need 64KB LDS -> 2 blocks/CU (vs 3), the
// m132 occupancy-loss trap. 3 blocks/CU TLP is the latency-hiding here.
__global__ __launch_bounds__(256) void gemm_bt_k(const u16* __restrict__ A,
                                                 const u16* __restrict__ B,
                                                 const float* __restrict__ bias,
                                                 u16* __restrict__ Cout,
                                                 u16* __restrict__ Vt,
                                                 int M, int N, int K) {
  __shared__ u16 As[128 * 64];
  __shared__ u16 Bs[128 * 64];
  const int tid = threadIdx.x;
  const int w = tid >> 6, lane = tid & 63;
  const int wm = w >> 1, wn = w & 1;
  const int orig = blockIdx.x;
  const int xcd = orig & 7, idx = orig >> 3;
  const int ni = idx >> 2, mi_ = idx & 3;
  const int m0 = (xcd * 4 + mi_) * 128, n0 = ni * 128;
  const int l15 = lane & 15, quad = lane >> 4;
  const int colr[2] = {(((quad) ^ (l15 & 7)) & 7) * 8,
                       (((4 + quad) ^ (l15 & 7)) & 7) * 8};

  int r_st[4], cs_st[4];
#pragma unroll
  for (int i = 0; i < 4; i++) {
    int idx2 = i * 256 + tid;
    r_st[i] = idx2 >> 3;
    cs_st[i] = ((idx2 & 7) ^ (r_st[i] & 7)) * 8;
  }

  f32x4 acc[4][4];
  const f32x4 zero = {0.f, 0.f, 0.f, 0.f};
#pragma unroll
  for (int i = 0; i < 4; i++)
#pragma unroll
    for (int j = 0; j < 4; j++) acc[i][j] = zero;

  for (int k0 = 0; k0 < K; k0 += 64) {
#pragma unroll
    for (int i = 0; i < 4; i++) {
      gll16(A + (size_t)(m0 + r_st[i]) * K + k0 + cs_st[i], &As[(i * 256 + w * 64) * 8]);
      gll16(B + (size_t)(n0 + r_st[i]) * K + k0 + cs_st[i], &Bs[(i * 256 + w * 64) * 8]);
    }
    __syncthreads();
#pragma unroll
    for (int kk = 0; kk < 2; kk++) {
      short8 af[4], bf[4];
#pragma unroll
      for (int i = 0; i < 4; i++) {
        af[i] = *(const short8*)&As[(wm * 64 + i * 16 + l15) * 64 + colr[kk]];
        bf[i] = *(const short8*)&Bs[(wn * 64 + i * 16 + l15) * 64 + colr[kk]];
      }
#pragma unroll
      for (int mi = 0; mi < 4; mi++)
#pragma unroll
        for (int ni2 = 0; ni2 < 4; ni2++)
          acc[mi][ni2] = __builtin_amdgcn_mfma_f32_16x16x32_bf16(af[mi], bf[ni2], acc[mi][ni2], 0, 0, 0);
    }
    __syncthreads();
  }

  const int cm = m0 + wm * 64, cn = n0 + wn * 64;
  if (n0 < 2048) {
    // Q/K region: row-major write into qkv
#pragma unroll
    for (int ni2 = 0; ni2 < 4; ni2++) {
      int n = cn + ni2 * 16 + l15;
      float bv = bias[n];
#pragma unroll
      for (int mi = 0; mi < 4; mi++) {
#pragma unroll
        for (int r = 0; r < 4; r++) {
          int m = cm + mi * 16 + quad * 4 + r;
          Cout[(size_t)m * N + n] = f2bf(acc[mi][ni2][r] + bv);
        }
      }
    }
  } else {
    // V region: write transposed directly to Vt [b][h][v][s]
    const int bidx = m0 >> 11;        // batch (block-uniform; 2048 % 128 == 0)
    const int sbase = (cm & 2047) + quad * 4;
#pragma unroll
    for (int ni2 = 0; ni2 < 4; ni2++) {
      const int n = cn + ni2 * 16 + l15;
      const int vg = n - 2048;        // h*64 + v
      const float bv = bias[n];
      u16* vbase = Vt + (size_t)(bidx * 1024 + vg) * 2048 + sbase;
#pragma unroll
      for (int mi = 0; mi < 4; mi++) {
        ushort4 pk;
        pk.x = f2bf(acc[mi][ni2][0] + bv);
        pk.y = f2bf(acc[mi][ni2][1] + bv);
        pk.z = f2bf(acc[mi][ni2][2] + bv);
        pk.w = f2bf(acc[mi][ni2][3] + bv);
        *(ushort4*)(vbase + mi * 16) = pk;
      }
    }
  }
}

// ---------------- GEMM 64x128 tile, BK=64, fp32 out, dbuf 1-barrier (R12) ----
// R12: ported attn_k's proven double-buffered single-barrier schedule:
// stage(t+1) issued BEFORE compute(t), one __syncthreads per K-iter (was 2).
// Staging latency now hides under the 16-MFMA compute phase instead of being
// drained cold by the barrier's vmcnt(0). LDS 24->48KB keeps exactly
// 2 blocks/CU (96 <= 160KB). Grid 512 = 8 XCDs x (8n x 8m).
__global__ __launch_bounds__(256) void gemm_bt64_k(const u16* __restrict__ A,
                                                   const u16* __restrict__ B,
                                                   const float* __restrict__ bias,
                                                   float* __restrict__ Cout,
                                                   int M, int N, int K) {
  __shared__ u16 As[2][64 * 64];
  __shared__ u16 Bs[2][128 * 64];
  const int tid = threadIdx.x;
  const int w = tid >> 6, lane = tid & 63;
  const int wm = w >> 1, wn = w & 1;
  const int orig = blockIdx.x;
  const int xcd = orig & 7, idx = orig >> 3;
  const int ni = idx >> 3, mi_ = idx & 7;
  const int m0 = (xcd * 8 + mi_) * 64, n0 = ni * 128;
  const int l15 = lane & 15, quad = lane >> 4;
  const int colr[2] = {(((quad) ^ (l15 & 7)) & 7) * 8,
                       (((4 + quad) ^ (l15 & 7)) & 7) * 8};

  // A: 64x64 = 4096 u16 -> 2 rounds; B: 128x64 = 8192 u16 -> 4 rounds
  int rA[2], cA[2], rB[4], cB[4];
#pragma unroll
  for (int i = 0; i < 2; i++) {
    int idx2 = i * 256 + tid;
    rA[i] = idx2 >> 3;
    cA[i] = ((idx2 & 7) ^ (rA[i] & 7)) * 8;
  }
#pragma unroll
  for (int i = 0; i < 4; i++) {
    int idx2 = i * 256 + tid;
    rB[i] = idx2 >> 3;
    cB[i] = ((idx2 & 7) ^ (rB[i] & 7)) * 8;
  }

  f32x4 acc[2][4];
  const f32x4 zero = {0.f, 0.f, 0.f, 0.f};
#pragma unroll
  for (int i = 0; i < 2; i++)
#pragma unroll
    for (int j = 0; j < 4; j++) acc[i][j] = zero;

  auto stage = [&](int bb, int k0) {
#pragma unroll
    for (int i = 0; i < 2; i++)
      gll16(A + (size_t)(m0 + rA[i]) * K + k0 + cA[i], &As[bb][(i * 256 + w * 64) * 8]);
#pragma unroll
    for (int i = 0; i < 4; i++)
      gll16(B + (size_t)(n0 + rB[i]) * K + k0 + cB[i], &Bs[bb][(i * 256 + w * 64) * 8]);
  };

  auto compute = [&](int bb) {
#pragma unroll
    for (int kk = 0; kk < 2; kk++) {
      short8 af[2], bf[4];
#pragma unroll
      for (int i = 0; i < 2; i++)
        af[i] = *(const short8*)&As[bb][(wm * 32 + i * 16 + l15) * 64 + colr[kk]];
#pragma unroll
      for (int j = 0; j < 4; j++)
        bf[j] = *(const short8*)&Bs[bb][(wn * 64 + j * 16 + l15) * 64 + colr[kk]];
#pragma unroll
      for (int i = 0; i < 2; i++)
#pragma unroll
        for (int j = 0; j < 4; j++)
          acc[i][j] = __builtin_amdgcn_mfma_f32_16x16x32_bf16(af[i], bf[j], acc[i][j], 0, 0, 0);
    }
  };

  stage(0, 0);
  int cur = 0;
  for (int t = 0; t < 15; t++) {
    __syncthreads();                 // drains stage(cur); waves done reading cur^1
    stage(cur ^ 1, (t + 1) * 64);    // prefetch next tile, overlaps compute
    compute(cur);
    cur ^= 1;
  }
  __syncthreads();
  compute(cur);

  const int cm = m0 + wm * 32, cn = n0 + wn * 64;
#pragma unroll
  for (int j = 0; j < 4; j++) {
    int n = cn + j * 16 + l15;
    float bv = bias[n];
#pragma unroll
    for (int i = 0; i < 2; i++) {
#pragma unroll
      for (int r = 0; r < 4; r++) {
        int m = cm + i * 16 + quad * 4 + r;
        Cout[(size_t)m * N + n] = acc[i][j][r] + bv;
      }
    }
  }
}

// ---------------- flash attention (R8 config, kept: proven ~57us floor) ------
// History: R6 killed LDS P-roundtrip (conflicts->0, no dur change). R7 doubled
// occupancy (no dur change). R8 XCD swizzle: FETCH 69.7->12.3MB (L2-resident)
// but dur -1.3us only. All pipes <50% -> issue/dependency floor under this
// schedule. Do not micro-tweak further; a different sync template would be
// needed for more.
__global__ __launch_bounds__(256, 4) void attn_k(const u16* __restrict__ qkv,
                                                 const u16* __restrict__ Vt,
                                                 u16* __restrict__ ctx) {
  __shared__ u16 Ks[2][64 * 64];
  __shared__ u16 Vs[2][64 * 64];
  const int tid = threadIdx.x;
  const int w = tid >> 6, lane = tid & 63;
  const int wq = w >> 1, wk = w & 1;
  const int l15 = lane & 15, quad = lane >> 4;

  // XCD-aware remap: xcd = orig%8 (dispatch round-robin); each xcd gets a
  // contiguous swz-range of 128 = 4 complete (b,h) groups of 32 q-blocks.
  const int orig = blockIdx.x;
  const int swz = (orig & 7) * 128 + (orig >> 3);
  const int q0 = (swz & 31) * 64;
  const int bh = swz >> 5;
  const int h = bh & 15, b = bh >> 4;

  short8 qf[2][2];
#pragma unroll
  for (int rt = 0; rt < 2; rt++) {
    const u16* qbase = qkv + (size_t)(b * S_ + q0 + wq * 32 + rt * 16 + l15) * 3072 + h * 64;
    qf[rt][0] = *(const short8*)(qbase + quad * 8);
    qf[rt][1] = *(const short8*)(qbase + 32 + quad * 8);
  }

  const int col0 = ((quad ^ (l15 & 7)) & 7) * 8;
  const int col1 = (((4 + quad) ^ (l15 & 7)) & 7) * 8;
  const int colw = wk ? col1 : col0;  // this wave's s-slice of V

  int r_st[2], cs_st[2];
#pragma unroll
  for (int i = 0; i < 2; i++) {
    int idx = i * 256 + tid;
    r_st[i] = idx >> 3;
    cs_st[i] = ((idx & 7) ^ (r_st[i] & 7)) * 8;
  }
  const u16* kp[2];
  const u16* vp[2];
#pragma unroll
  for (int i = 0; i < 2; i++) {
    kp[i] = qkv + (size_t)(b * S_ + r_st[i]) * 3072 + 1024 + h * 64 + cs_st[i];
    vp[i] = Vt + ((size_t)(b * H_ + h) * 64 + r_st[i]) * S_ + cs_st[i];
  }

  const f32x4 zero = {0.f, 0.f, 0.f, 0.f};
  f32x4 o[2][4];
#pragma unroll
  for (int rt = 0; rt < 2; rt++)
#pragma unroll
    for (int i = 0; i < 4; i++) o[rt][i] = zero;
  float lsum[2] = {0.f, 0.f};

  auto stage = [&](int bb, int t) {
#pragma unroll
    for (int i = 0; i < 2; i++) {
      gll16(kp[i] + (size_t)t * 64 * 3072, &Ks[bb][(i * 256 + w * 64) * 8]);
      gll16(vp[i] + t * 64, &Vs[bb][(i * 256 + w * 64) * 8]);
    }
  };

  auto compute = [&](int bb) {
    short8 kf[2][2];
#pragma unroll
    for (int kb = 0; kb < 2; kb++) {
      const int krow = (wk * 32 + kb * 16 + l15) * 64;
      kf[kb][0] = *(const short8*)&Ks[bb][krow + col0];
      kf[kb][1] = *(const short8*)&Ks[bb][krow + col1];
    }
    short8 pf[2];
#pragma unroll
    for (int rt = 0; rt < 2; rt++) {
      uint32_t Sx[2][2];
      __builtin_amdgcn_s_setprio(1);
#pragma unroll
      for (int kb = 0; kb < 2; kb++) {
        f32x4 st = __builtin_amdgcn_mfma_f32_16x16x32_bf16(kf[kb][0], qf[rt][0], zero, 0, 0, 0);
        st = __builtin_amdgcn_mfma_f32_16x16x32_bf16(kf[kb][1], qf[rt][1], st, 0, 0, 0);
        __builtin_amdgcn_s_setprio(0);
        float p0 = fexp2(st[0]), p1 = fexp2(st[1]), p2 = fexp2(st[2]), p3 = fexp2(st[3]);
        lsum[rt] += (p0 + p1) + (p2 + p3);
        Sx[kb][0] = pk_bf16(p0, p1);  // k = kb*16 + quad*4 + {0,1}
        Sx[kb][1] = pk_bf16(p2, p3);  // k = kb*16 + quad*4 + {2,3}
      }
#pragma unroll
      for (int s = 0; s < 2; s++)
        asm volatile("v_permlane32_swap_b32 %0, %1" : "+v"(Sx[0][s]), "+v"(Sx[1][s]));
#pragma unroll
      for (int s = 0; s < 2; s++)
        asm volatile("v_permlane16_swap_b32 %0, %1" : "+v"(Sx[0][s]), "+v"(Sx[1][s]));
      union { uint32_t u[4]; short8 s8; } cv;
      cv.u[0] = Sx[0][0]; cv.u[1] = Sx[0][1];
      cv.u[2] = Sx[1][0]; cv.u[3] = Sx[1][1];
      pf[rt] = cv.s8;
    }
    __builtin_amdgcn_s_setprio(1);
#pragma unroll
    for (int vi = 0; vi < 4; vi++) {
      short8 vf = *(const short8*)&Vs[bb][(vi * 16 + l15) * 64 + colw];
      o[0][vi] = __builtin_amdgcn_mfma_f32_16x16x32_bf16(vf, pf[0], o[0][vi], 0, 0, 0);
      o[1][vi] = __builtin_amdgcn_mfma_f32_16x16x32_bf16(vf, pf[1], o[1][vi], 0, 0, 0);
    }
    __builtin_amdgcn_s_setprio(0);
  };

  stage(0, 0);
  for (int t = 0; t < 31; t++) {
    __syncthreads();
    stage((t + 1) & 1, t + 1);
    compute(t & 1);
  }
  __syncthreads();
  compute(1);

  // ---- cross-wave (wk) reduction of O and lsum through freed LDS ----
  float ls[2];
#pragma unroll
  for (int rt = 0; rt < 2; rt++) {
    float l = lsum[rt];
    l += __shfl_xor(l, 16);
    l += __shfl_xor(l, 32);
    ls[rt] = l;
  }
  __syncthreads();  // all compute reads of Ks/Vs done before reuse
  float* red = (float*)&Ks[0][0];   // 16 KB: 2 wq-waves x 8 KB
  float* redl = (float*)&Vs[0][0];  // 1 KB
  if (wk == 1) {
#pragma unroll
    for (int rt = 0; rt < 2; rt++) {
#pragma unroll
      for (int vi = 0; vi < 4; vi++)
        *(f32x4*)(red + wq * 2048 + (rt * 4 + vi) * 256 + lane * 4) = o[rt][vi];
      redl[wq * 128 + rt * 64 + lane] = ls[rt];
    }
  }
  __syncthreads();
  if (wk == 0) {
#pragma unroll
    for (int rt = 0; rt < 2; rt++) {
      const float tot = ls[rt] + redl[wq * 128 + rt * 64 + lane];
      const float inv = 1.f / tot;
      u16* cbase = ctx + (size_t)(b * S_ + q0 + wq * 32 + rt * 16 + l15) * 1024 + h * 64;
#pragma unroll
      for (int vi = 0; vi < 4; vi++) {
        f32x4 p = *(f32x4*)(red + wq * 2048 + (rt * 4 + vi) * 256 + lane * 4);
        f32x4 s = o[rt][vi] + p;
        ushort4 pk;
        pk.x = f2bf(s[0] * inv);
        pk.y = f2bf(s[1] * inv);
        pk.z = f2bf(s[2] * inv);
        pk.w = f2bf(s[3] * inv);
        *(ushort4*)(cbase + vi * 16 + quad * 4) = pk;
      }
    }
  }
}

extern "C" void kernel_launch(void* const* d_in, const int* in_sizes, int n_in,
                              void* d_out, int out_size, void* d_ws, size_t ws_size,
                              hipStream_t stream) {
  const float* hidden = (const float*)d_in[0];
  const float* Wq = (const float*)d_in[1];
  const float* bq = (const float*)d_in[2];
  const float* Wk = (const float*)d_in[3];
  const float* bk = (const float*)d_in[4];
  const float* Wv = (const float*)d_in[5];
  const float* bv = (const float*)d_in[6];
  const float* Wo = (const float*)d_in[7];
  const float* bo = (const float*)d_in[8];
  float* out = (float*)d_out;

  char* ws = (char*)d_ws;
  u16* Abf = (u16*)(ws + 0);                 // 4096x1024 bf16   (8,388,608)
  u16* Wt = (u16*)(ws + 8388608);            // 3072x1024 bf16   (6,291,456)
  u16* Wot = (u16*)(ws + 14680064);          // 1024x1024 bf16   (2,097,152)
  float* biasQKV = (float*)(ws + 16777216);  // 3072 fp32        (12,288 padded)
  u16* qkv = (u16*)(ws + 16789504);          // 4096x3072 bf16   (25,165,824; V third unused)
  u16* Vt = (u16*)(ws + 41955328);           // [b][h][64][2048] (8,388,608)
  u16* ctx = (u16*)(ws + 50343936);          // 4096x1024 bf16   (8,388,608)

  // fused prep: cast + Wq/Wk/Wv transpose + bias + Wo transpose
  prep_k<<<3072, 256, 0, stream>>>(hidden, Wq, Wk, Wv, bq, bk, bv, Wo,
                                   Abf, Wt, Wot, biasQKV);

  // QKV projection: [4096,1024] x [3072,1024]^T -> qkv (Q,K) + Vt (V, fused
  // transpose). Flat grid, XCD-aware decode inside.
  gemm_bt_k<<<dim3(768), 256, 0, stream>>>(Abf, Wt, biasQKV, qkv, Vt, 4096, 3072, 1024);

  // flash attention -> ctx [4096, 1024] bf16  (flat grid, XCD-aware swizzle)
  attn_k<<<dim3(1024), 256, 0, stream>>>(qkv, Vt, ctx);

  // output projection: [4096,1024] x [1024,1024]^T + bo -> fp32 out
  // (BK=64, dbuf single-barrier schedule)
  gemm_bt64_k<<<dim3(512), 256, 0, stream>>>(ctx, Wot, bo, out, 4096, 1024, 1024);
}